// Round 12
// baseline (371.729 us; speedup 1.0000x reference)
//
#include <hip/hip_runtime.h>
#include <hip/hip_fp16.h>
#include <math.h>

// TransformerConvNet: 2x TransformerConv(heads=1) + ELU + MLP head + log_softmax
// N=100000 nodes, E=1600000 edges, F_IN=64, C1=32, C2=64, H1=128, NC=10
//
// R12: conv_fused at 4 channels/lane — float4 kv gathers (16 B/lane), 4-8
// edges in flight per wave, reduce shrunk to 3-4 shuffle steps. CSR build +
// MFMA linears unchanged.

#define SCAN_NB 256

typedef _Float16 half8 __attribute__((ext_vector_type(8)));
typedef float f32x4 __attribute__((ext_vector_type(4)));

// ---------- CSR build ----------
__global__ __launch_bounds__(256)
void count_rank_kernel(const int* __restrict__ dst, int* __restrict__ deg,
                       int* __restrict__ rank, int e) {
    for (int i = blockIdx.x * 256 + threadIdx.x; i < e; i += gridDim.x * 256)
        rank[i] = atomicAdd(deg + dst[i], 1);
}

__global__ __launch_bounds__(256)
void blocksum_kernel(const int* __restrict__ deg, int* __restrict__ bsum, int n) {
    __shared__ int ls[256];
    const int chunk = (n + gridDim.x - 1) / gridDim.x;
    const int b0 = blockIdx.x * chunk;
    const int b1 = (b0 + chunk < n) ? b0 + chunk : n;
    int s = 0;
    for (int i = b0 + threadIdx.x; i < b1; i += 256) s += deg[i];
    ls[threadIdx.x] = s;
    __syncthreads();
    for (int off = 128; off > 0; off >>= 1) {
        if (threadIdx.x < off) ls[threadIdx.x] += ls[threadIdx.x + off];
        __syncthreads();
    }
    if (threadIdx.x == 0) bsum[blockIdx.x] = ls[0];
}

__global__ __launch_bounds__(256)
void scanb_kernel(const int* __restrict__ bsum, int* __restrict__ boff,
                  int* __restrict__ total, int nb) {
    __shared__ int ls[256];
    const int t = threadIdx.x;
    int v = (t < nb) ? bsum[t] : 0;
    ls[t] = v;
    __syncthreads();
    for (int off = 1; off < 256; off <<= 1) {
        int u = (t >= off) ? ls[t - off] : 0;
        __syncthreads();
        ls[t] += u;
        __syncthreads();
    }
    if (t < nb) boff[t] = ls[t] - v;
    if (t == 255) *total = ls[255];
}

__global__ __launch_bounds__(256)
void writeptr_kernel(const int* __restrict__ deg, const int* __restrict__ boff,
                     int* __restrict__ rowptr, int n) {
    __shared__ int ls[256];
    const int chunk = (n + gridDim.x - 1) / gridDim.x;
    const int b0 = blockIdx.x * chunk;
    const int b1 = (b0 + chunk < n) ? b0 + chunk : n;
    const int tchunk = (chunk + 255) / 256;
    const int t0 = b0 + threadIdx.x * tchunk;
    const int t1 = (t0 + tchunk < b1) ? t0 + tchunk : b1;
    int s = 0;
    for (int i = t0; i < t1; ++i) s += deg[i];
    ls[threadIdx.x] = s;
    __syncthreads();
    for (int off = 1; off < 256; off <<= 1) {
        int u = (threadIdx.x >= off) ? ls[threadIdx.x - off] : 0;
        __syncthreads();
        ls[threadIdx.x] += u;
        __syncthreads();
    }
    int run = boff[blockIdx.x] + ls[threadIdx.x] - s;
    for (int i = t0; i < t1; ++i) { rowptr[i] = run; run += deg[i]; }
}

__global__ __launch_bounds__(256)
void fill_pack_kernel(const int* __restrict__ src, const int* __restrict__ dst,
                      const float* __restrict__ eattr,
                      const int* __restrict__ rowptr, const int* __restrict__ rank,
                      int2* __restrict__ ecsr, int e) {
    for (int i = blockIdx.x * 256 + threadIdx.x; i < e; i += gridDim.x * 256) {
        int p = rowptr[dst[i]] + rank[i];
        ecsr[p] = make_int2(src[i], __float_as_int(eattr[i]));
    }
}

// ---------- linear4 via MFMA: q | s (fp32) + kv (__half2) ----------
template<int FIN, int C>
__global__ __launch_bounds__(256, 2)
void linear4_mfma_kernel(const float* __restrict__ X,
                         const float* __restrict__ Wq, const float* __restrict__ bq,
                         const float* __restrict__ Wk, const float* __restrict__ bk,
                         const float* __restrict__ Wv, const float* __restrict__ bv,
                         const float* __restrict__ Ws, const float* __restrict__ bs,
                         float* __restrict__ q, __half2* __restrict__ kv,
                         float* __restrict__ s, int n)
{
    constexpr int FOURC = 4 * C;
    constexpr int P  = FIN + 16;
    constexpr int KT = FIN / 32;
    constexpr int NT = FOURC / 16;
    __shared__ _Float16 wsh[FOURC * P] __attribute__((aligned(16)));
    __shared__ float bsh[FOURC];

    for (int i = threadIdx.x; i < FOURC * FIN; i += 256) {
        int col = i / FIN, f = i - (i / FIN) * FIN;
        float w;
        if (col < C)          w = Wq[f * C + col];
        else if (col < 2 * C) w = Ws[f * C + col - C];
        else if (col < 3 * C) w = Wk[f * C + col - 2 * C];
        else                  w = Wv[f * C + col - 3 * C];
        wsh[col * P + f] = (_Float16)w;
    }
    for (int i = threadIdx.x; i < FOURC; i += 256) {
        bsh[i] = (i < C) ? bq[i] : (i < 2 * C) ? bs[i - C]
               : (i < 3 * C) ? bk[i - 2 * C] : bv[i - 3 * C];
    }
    __syncthreads();

    const int lane = threadIdx.x & 63;
    const int wid  = threadIdx.x >> 6;
    const int m = lane & 15, g = lane >> 4;

    half8 bfrag[KT][NT];
    #pragma unroll
    for (int kt = 0; kt < KT; ++kt)
        #pragma unroll
        for (int nt = 0; nt < NT; ++nt)
            bfrag[kt][nt] = *reinterpret_cast<const half8*>(
                &wsh[(nt * 16 + m) * P + kt * 32 + g * 8]);

    const int tiles = n >> 4;   // N divisible by 16
    for (int t = blockIdx.x * 4 + wid; t < tiles; t += gridDim.x * 4) {
        const int row0 = t * 16;
        const float* xr = X + (size_t)(row0 + m) * FIN + g * 8;
        half8 afrag[KT];
        #pragma unroll
        for (int kt = 0; kt < KT; ++kt) {
            float4 u = *reinterpret_cast<const float4*>(xr + kt * 32);
            float4 w = *reinterpret_cast<const float4*>(xr + kt * 32 + 4);
            afrag[kt] = half8{(_Float16)u.x, (_Float16)u.y, (_Float16)u.z, (_Float16)u.w,
                              (_Float16)w.x, (_Float16)w.y, (_Float16)w.z, (_Float16)w.w};
        }
        #pragma unroll
        for (int nt = 0; nt < 2 * C / 16; ++nt) {
            f32x4 acc = {0.f, 0.f, 0.f, 0.f};
            #pragma unroll
            for (int kt = 0; kt < KT; ++kt)
                acc = __builtin_amdgcn_mfma_f32_16x16x32_f16(afrag[kt], bfrag[kt][nt], acc, 0, 0, 0);
            const int col = nt * 16 + m;
            const float bias = bsh[col];
            float* outp = (nt < C / 16) ? q : s;
            const int cc = (nt < C / 16) ? col : col - C;
            #pragma unroll
            for (int r = 0; r < 4; ++r)
                outp[(size_t)(row0 + g * 4 + r) * C + cc] = acc[r] + bias;
        }
        #pragma unroll
        for (int t2 = 0; t2 < C / 16; ++t2) {
            const int ntK = 2 * C / 16 + t2, ntV = 3 * C / 16 + t2;
            f32x4 aK = {0.f, 0.f, 0.f, 0.f}, aV = {0.f, 0.f, 0.f, 0.f};
            #pragma unroll
            for (int kt = 0; kt < KT; ++kt) {
                aK = __builtin_amdgcn_mfma_f32_16x16x32_f16(afrag[kt], bfrag[kt][ntK], aK, 0, 0, 0);
                aV = __builtin_amdgcn_mfma_f32_16x16x32_f16(afrag[kt], bfrag[kt][ntV], aV, 0, 0, 0);
            }
            const int ck = t2 * 16 + m;
            const float bK = bsh[2 * C + ck], bV = bsh[3 * C + ck];
            #pragma unroll
            for (int r = 0; r < 4; ++r)
                kv[(size_t)(row0 + g * 4 + r) * C + ck] = __floats2half2_rn(aK[r] + bK, aV[r] + bV);
        }
    }
}

// ---------- fc1 via MFMA: fp32 out + ELU ----------
template<int FIN, int COUT>
__global__ __launch_bounds__(256, 2)
void linear_mfma_kernel(const float* __restrict__ X, const float* __restrict__ W,
                        const float* __restrict__ b, float* __restrict__ out, int n)
{
    constexpr int P  = FIN + 16;
    constexpr int KT = FIN / 32;
    constexpr int NT = COUT / 16;
    __shared__ _Float16 wsh[COUT * P] __attribute__((aligned(16)));
    __shared__ float bsh[COUT];
    for (int i = threadIdx.x; i < COUT * FIN; i += 256) {
        int col = i / FIN, f = i - (i / FIN) * FIN;
        wsh[col * P + f] = (_Float16)W[f * COUT + col];
    }
    for (int i = threadIdx.x; i < COUT; i += 256) bsh[i] = b[i];
    __syncthreads();

    const int lane = threadIdx.x & 63;
    const int wid  = threadIdx.x >> 6;
    const int m = lane & 15, g = lane >> 4;

    half8 bfrag[KT][NT];
    #pragma unroll
    for (int kt = 0; kt < KT; ++kt)
        #pragma unroll
        for (int nt = 0; nt < NT; ++nt)
            bfrag[kt][nt] = *reinterpret_cast<const half8*>(
                &wsh[(nt * 16 + m) * P + kt * 32 + g * 8]);

    const int tiles = n >> 4;
    for (int t = blockIdx.x * 4 + wid; t < tiles; t += gridDim.x * 4) {
        const int row0 = t * 16;
        const float* xr = X + (size_t)(row0 + m) * FIN + g * 8;
        half8 afrag[KT];
        #pragma unroll
        for (int kt = 0; kt < KT; ++kt) {
            float4 u = *reinterpret_cast<const float4*>(xr + kt * 32);
            float4 w = *reinterpret_cast<const float4*>(xr + kt * 32 + 4);
            afrag[kt] = half8{(_Float16)u.x, (_Float16)u.y, (_Float16)u.z, (_Float16)u.w,
                              (_Float16)w.x, (_Float16)w.y, (_Float16)w.z, (_Float16)w.w};
        }
        #pragma unroll
        for (int nt = 0; nt < NT; ++nt) {
            f32x4 acc = {0.f, 0.f, 0.f, 0.f};
            #pragma unroll
            for (int kt = 0; kt < KT; ++kt)
                acc = __builtin_amdgcn_mfma_f32_16x16x32_f16(afrag[kt], bfrag[kt][nt], acc, 0, 0, 0);
            const int col = nt * 16 + m;
            const float bias = bsh[col];
            #pragma unroll
            for (int r = 0; r < 4; ++r) {
                float hv = acc[r] + bias;
                hv = (hv > 0.f) ? hv : expm1f(hv);
                out[(size_t)(row0 + g * 4 + r) * COUT + col] = hv;
            }
        }
    }
}

// ---------- fused conv: 4 channels/lane, no-max softmax + skip + ELU ----------
template<int C>
__global__ __launch_bounds__(256)
void conv_fused_kernel(const int* __restrict__ rowptr, const int2* __restrict__ ecsr,
                       const float* __restrict__ q, const __half2* __restrict__ kv,
                       const float* __restrict__ sres,
                       const float* __restrict__ We, const float* __restrict__ be,
                       float* __restrict__ h, float scale, int n)
{
    constexpr int LPE    = C / 4;             // lanes per edge (16 or 8)
    constexpr int EPI    = 64 / LPE;          // edges in flight per wave (4 or 8)
    constexpr int LOG    = (C == 64) ? 4 : 3; // log2(LPE)
    constexpr int UNROLL = 4;
    const int wave = threadIdx.x >> 6;
    const int lane = threadIdx.x & 63;
    const int l    = lane & (LPE - 1);
    const int slot = lane >> LOG;
    const int c0   = 4 * l;
    const int node = blockIdx.x * 4 + wave;
    if (node >= n) return;

    const float4 wec = *reinterpret_cast<const float4*>(We + c0);
    const float4 bec = *reinterpret_cast<const float4*>(be + c0);
    const float4 qp  = *reinterpret_cast<const float4*>(q + (size_t)node * C + c0);
    const int r0 = rowptr[node], r1 = rowptr[node + 1];

    float ssum = 0.f;
    float a0 = 0.f, a1 = 0.f, a2 = 0.f, a3 = 0.f;
    int j = r0 + slot;
    for (; j + (UNROLL - 1) * EPI < r1; j += UNROLL * EPI) {
        int2 epk[UNROLL]; float4 kvr[UNROLL];
        #pragma unroll
        for (int u = 0; u < UNROLL; ++u) epk[u] = ecsr[j + u * EPI];
        #pragma unroll
        for (int u = 0; u < UNROLL; ++u)
            kvr[u] = *reinterpret_cast<const float4*>(kv + (size_t)epk[u].x * C + c0);
        #pragma unroll
        for (int u = 0; u < UNROLL; ++u) {
            float ea = __int_as_float(epk[u].y);
            float e0 = fmaf(ea, wec.x, bec.x);
            float e1 = fmaf(ea, wec.y, bec.y);
            float e2 = fmaf(ea, wec.z, bec.z);
            float e3 = fmaf(ea, wec.w, bec.w);
            float2 f0 = __half22float2(*reinterpret_cast<__half2*>(&kvr[u].x));
            float2 f1 = __half22float2(*reinterpret_cast<__half2*>(&kvr[u].y));
            float2 f2 = __half22float2(*reinterpret_cast<__half2*>(&kvr[u].z));
            float2 f3 = __half22float2(*reinterpret_cast<__half2*>(&kvr[u].w));
            float p = qp.x * (f0.x + e0);
            p = fmaf(qp.y, f1.x + e1, p);
            p = fmaf(qp.z, f2.x + e2, p);
            p = fmaf(qp.w, f3.x + e3, p);
            #pragma unroll
            for (int off = LPE >> 1; off > 0; off >>= 1) p += __shfl_xor(p, off);
            float w = __expf(p * scale);
            ssum += w;
            a0 = fmaf(w, f0.y + e0, a0);
            a1 = fmaf(w, f1.y + e1, a1);
            a2 = fmaf(w, f2.y + e2, a2);
            a3 = fmaf(w, f3.y + e3, a3);
        }
    }
    for (; j < r1; j += EPI) {
        int2 epk = ecsr[j];
        float4 kvr = *reinterpret_cast<const float4*>(kv + (size_t)epk.x * C + c0);
        float ea = __int_as_float(epk.y);
        float e0 = fmaf(ea, wec.x, bec.x);
        float e1 = fmaf(ea, wec.y, bec.y);
        float e2 = fmaf(ea, wec.z, bec.z);
        float e3 = fmaf(ea, wec.w, bec.w);
        float2 f0 = __half22float2(*reinterpret_cast<__half2*>(&kvr.x));
        float2 f1 = __half22float2(*reinterpret_cast<__half2*>(&kvr.y));
        float2 f2 = __half22float2(*reinterpret_cast<__half2*>(&kvr.z));
        float2 f3 = __half22float2(*reinterpret_cast<__half2*>(&kvr.w));
        float p = qp.x * (f0.x + e0);
        p = fmaf(qp.y, f1.x + e1, p);
        p = fmaf(qp.z, f2.x + e2, p);
        p = fmaf(qp.w, f3.x + e3, p);
        #pragma unroll
        for (int off = LPE >> 1; off > 0; off >>= 1) p += __shfl_xor(p, off);
        float w = __expf(p * scale);
        ssum += w;
        a0 = fmaf(w, f0.y + e0, a0);
        a1 = fmaf(w, f1.y + e1, a1);
        a2 = fmaf(w, f2.y + e2, a2);
        a3 = fmaf(w, f3.y + e3, a3);
    }

    // merge the EPI slot streams (plain sums — no max)
    #pragma unroll
    for (int off = LPE; off < 64; off <<= 1) {
        ssum += __shfl_xor(ssum, off);
        a0   += __shfl_xor(a0, off);
        a1   += __shfl_xor(a1, off);
        a2   += __shfl_xor(a2, off);
        a3   += __shfl_xor(a3, off);
    }

    if (slot == 0) {
        float inv = 1.f / (ssum + 1e-16f);
        float4 sr = *reinterpret_cast<const float4*>(sres + (size_t)node * C + c0);
        float h0 = fmaf(a0, inv, sr.x);
        float h1 = fmaf(a1, inv, sr.y);
        float h2v = fmaf(a2, inv, sr.z);
        float h3 = fmaf(a3, inv, sr.w);
        h0 = (h0 > 0.f) ? h0 : expm1f(h0);
        h1 = (h1 > 0.f) ? h1 : expm1f(h1);
        h2v = (h2v > 0.f) ? h2v : expm1f(h2v);
        h3 = (h3 > 0.f) ? h3 : expm1f(h3);
        *reinterpret_cast<float4*>(h + (size_t)node * C + c0) = make_float4(h0, h1, h2v, h3);
    }
}

// ---------- fc2 + log_softmax ----------
#define H1_DIM 128
#define NC_DIM 10
__global__ __launch_bounds__(256)
void head_kernel(const float* __restrict__ Hf, const float* __restrict__ W,
                 const float* __restrict__ b, float* __restrict__ out, int n)
{
    __shared__ float wsh[H1_DIM * NC_DIM];
    __shared__ float bsh[NC_DIM];
    for (int i = threadIdx.x; i < H1_DIM * NC_DIM; i += 256) wsh[i] = W[i];
    for (int i = threadIdx.x; i < NC_DIM; i += 256) bsh[i] = b[i];
    __syncthreads();
    for (int row = blockIdx.x * 256 + threadIdx.x; row < n; row += gridDim.x * 256) {
        const float* hr = Hf + (size_t)row * H1_DIM;
        float logit[NC_DIM];
        #pragma unroll
        for (int c = 0; c < NC_DIM; ++c) logit[c] = bsh[c];
        for (int f = 0; f < H1_DIM; ++f) {
            float xv = hr[f];
            #pragma unroll
            for (int c = 0; c < NC_DIM; ++c) logit[c] = fmaf(xv, wsh[f * NC_DIM + c], logit[c]);
        }
        float m = logit[0];
        #pragma unroll
        for (int c = 1; c < NC_DIM; ++c) m = fmaxf(m, logit[c]);
        float sum = 0.f;
        #pragma unroll
        for (int c = 0; c < NC_DIM; ++c) sum += __expf(logit[c] - m);
        float lse = m + logf(sum);
        #pragma unroll
        for (int c = 0; c < NC_DIM; ++c) out[(size_t)row * NC_DIM + c] = logit[c] - lse;
    }
}

extern "C" void kernel_launch(void* const* d_in, const int* in_sizes, int n_in,
                              void* d_out, int out_size, void* d_ws, size_t ws_size,
                              hipStream_t stream) {
    const float* x   = (const float*)d_in[0];
    const int*   ei  = (const int*)d_in[1];
    const float* ea  = (const float*)d_in[2];
    const float *Wq1 = (const float*)d_in[3],  *bq1 = (const float*)d_in[4];
    const float *Wk1 = (const float*)d_in[5],  *bk1 = (const float*)d_in[6];
    const float *Wv1 = (const float*)d_in[7],  *bv1 = (const float*)d_in[8];
    const float *We1 = (const float*)d_in[9],  *be1 = (const float*)d_in[10];
    const float *Ws1 = (const float*)d_in[11], *bs1 = (const float*)d_in[12];
    const float *Wq2 = (const float*)d_in[13], *bq2 = (const float*)d_in[14];
    const float *Wk2 = (const float*)d_in[15], *bk2 = (const float*)d_in[16];
    const float *Wv2 = (const float*)d_in[17], *bv2 = (const float*)d_in[18];
    const float *We2 = (const float*)d_in[19], *be2 = (const float*)d_in[20];
    const float *Ws2 = (const float*)d_in[21], *bs2 = (const float*)d_in[22];
    const float *Wf1 = (const float*)d_in[23], *bf1 = (const float*)d_in[24];
    const float *Wf2 = (const float*)d_in[25], *bf2 = (const float*)d_in[26];

    const int N = in_sizes[0] / 64;   // 100000
    const int E = in_sizes[2];        // 1600000
    const int* src = ei;              // edge_index[0]
    const int* dst = ei + E;          // edge_index[1]

    float* wsf = (float*)d_ws;
    const size_t N64 = (size_t)N * 64;
    float* q      = wsf;                      // N*64
    __half2* kv   = (__half2*)(q + N64);      // N*64 half2 (k,v packed)
    float* s      = (float*)(kv + N64);       // N*64 (skip proj)
    float* h1     = s + N64;                  // N*32
    float* h2     = h1 + (size_t)N * 32;      // N*64
    int* deg      = (int*)(h2 + N64);         // N
    int* rowptr   = deg + N;                  // N+1
    int* bsum     = rowptr + N + 1;           // SCAN_NB
    int* boff     = bsum + SCAN_NB;           // SCAN_NB
    int* rank     = boff + SCAN_NB;           // E
    int2* ecsr    = (int2*)(rank + E);        // E (packed {src, eattr})
    float* hfc    = wsf;                      // N*128 (reuses dead q after conv2)

    float* out = (float*)d_out;

    // ---- CSR build ----
    hipMemsetAsync(deg, 0, (size_t)N * 4, stream);
    count_rank_kernel<<<2048, 256, 0, stream>>>(dst, deg, rank, E);
    blocksum_kernel<<<SCAN_NB, 256, 0, stream>>>(deg, bsum, N);
    scanb_kernel<<<1, 256, 0, stream>>>(bsum, boff, rowptr + N, SCAN_NB);
    writeptr_kernel<<<SCAN_NB, 256, 0, stream>>>(deg, boff, rowptr, N);
    fill_pack_kernel<<<4096, 256, 0, stream>>>(src, dst, ea, rowptr, rank, ecsr, E);

    const int convGrid = (N + 3) / 4;

    // ---- layer 1 (C=32) ----
    linear4_mfma_kernel<64, 32><<<1024, 256, 0, stream>>>(
        x, Wq1, bq1, Wk1, bk1, Wv1, bv1, Ws1, bs1, q, kv, s, N);
    conv_fused_kernel<32><<<convGrid, 256, 0, stream>>>(
        rowptr, ecsr, q, kv, s, We1, be1, h1, 0.17677669529663687f, N);

    // ---- layer 2 (C=64) ----
    linear4_mfma_kernel<32, 64><<<1024, 256, 0, stream>>>(
        h1, Wq2, bq2, Wk2, bk2, Wv2, bv2, Ws2, bs2, q, kv, s, N);
    conv_fused_kernel<64><<<convGrid, 256, 0, stream>>>(
        rowptr, ecsr, q, kv, s, We2, be2, h2, 0.125f, N);

    // ---- MLP head ----
    linear_mfma_kernel<64, 128><<<1024, 256, 0, stream>>>(h2, Wf1, bf1, hfc, N);
    head_kernel<<<512, 256, 0, stream>>>(hfc, Wf2, bf2, out, N);
}

// Round 13
// 350.725 us; speedup vs baseline: 1.0599x; 1.0599x over previous
//
#include <hip/hip_runtime.h>
#include <hip/hip_fp16.h>
#include <math.h>

// TransformerConvNet: 2x TransformerConv(heads=1) + ELU + MLP head + log_softmax
// N=100000 nodes, E=1600000 edges, F_IN=64, C1=32, C2=64, H1=128, NC=10
//
// R13: conv_fused back to 2 ch/lane (R11 geometry, best occupancy) with
// (a) e-term factored out of the edge loop (d1=q.We, d0=q.be per node;
//     epilogue adds We*sum(w*ea)+be*sum(w)), and
// (b) masked UNROLL=4 loop — no serial remainder tail.

#define SCAN_NB 256

typedef _Float16 half8 __attribute__((ext_vector_type(8)));
typedef float f32x4 __attribute__((ext_vector_type(4)));

// ---------- CSR build ----------
__global__ __launch_bounds__(256)
void count_rank_kernel(const int* __restrict__ dst, int* __restrict__ deg,
                       int* __restrict__ rank, int e) {
    for (int i = blockIdx.x * 256 + threadIdx.x; i < e; i += gridDim.x * 256)
        rank[i] = atomicAdd(deg + dst[i], 1);
}

__global__ __launch_bounds__(256)
void blocksum_kernel(const int* __restrict__ deg, int* __restrict__ bsum, int n) {
    __shared__ int ls[256];
    const int chunk = (n + gridDim.x - 1) / gridDim.x;
    const int b0 = blockIdx.x * chunk;
    const int b1 = (b0 + chunk < n) ? b0 + chunk : n;
    int s = 0;
    for (int i = b0 + threadIdx.x; i < b1; i += 256) s += deg[i];
    ls[threadIdx.x] = s;
    __syncthreads();
    for (int off = 128; off > 0; off >>= 1) {
        if (threadIdx.x < off) ls[threadIdx.x] += ls[threadIdx.x + off];
        __syncthreads();
    }
    if (threadIdx.x == 0) bsum[blockIdx.x] = ls[0];
}

__global__ __launch_bounds__(256)
void scanb_kernel(const int* __restrict__ bsum, int* __restrict__ boff,
                  int* __restrict__ total, int nb) {
    __shared__ int ls[256];
    const int t = threadIdx.x;
    int v = (t < nb) ? bsum[t] : 0;
    ls[t] = v;
    __syncthreads();
    for (int off = 1; off < 256; off <<= 1) {
        int u = (t >= off) ? ls[t - off] : 0;
        __syncthreads();
        ls[t] += u;
        __syncthreads();
    }
    if (t < nb) boff[t] = ls[t] - v;
    if (t == 255) *total = ls[255];
}

__global__ __launch_bounds__(256)
void writeptr_kernel(const int* __restrict__ deg, const int* __restrict__ boff,
                     int* __restrict__ rowptr, int n) {
    __shared__ int ls[256];
    const int chunk = (n + gridDim.x - 1) / gridDim.x;
    const int b0 = blockIdx.x * chunk;
    const int b1 = (b0 + chunk < n) ? b0 + chunk : n;
    const int tchunk = (chunk + 255) / 256;
    const int t0 = b0 + threadIdx.x * tchunk;
    const int t1 = (t0 + tchunk < b1) ? t0 + tchunk : b1;
    int s = 0;
    for (int i = t0; i < t1; ++i) s += deg[i];
    ls[threadIdx.x] = s;
    __syncthreads();
    for (int off = 1; off < 256; off <<= 1) {
        int u = (threadIdx.x >= off) ? ls[threadIdx.x - off] : 0;
        __syncthreads();
        ls[threadIdx.x] += u;
        __syncthreads();
    }
    int run = boff[blockIdx.x] + ls[threadIdx.x] - s;
    for (int i = t0; i < t1; ++i) { rowptr[i] = run; run += deg[i]; }
}

__global__ __launch_bounds__(256)
void fill_pack_kernel(const int* __restrict__ src, const int* __restrict__ dst,
                      const float* __restrict__ eattr,
                      const int* __restrict__ rowptr, const int* __restrict__ rank,
                      int2* __restrict__ ecsr, int e) {
    for (int i = blockIdx.x * 256 + threadIdx.x; i < e; i += gridDim.x * 256) {
        int p = rowptr[dst[i]] + rank[i];
        ecsr[p] = make_int2(src[i], __float_as_int(eattr[i]));
    }
}

// ---------- linear4 via MFMA: q | s (fp32) + kv (__half2) ----------
template<int FIN, int C>
__global__ __launch_bounds__(256, 2)
void linear4_mfma_kernel(const float* __restrict__ X,
                         const float* __restrict__ Wq, const float* __restrict__ bq,
                         const float* __restrict__ Wk, const float* __restrict__ bk,
                         const float* __restrict__ Wv, const float* __restrict__ bv,
                         const float* __restrict__ Ws, const float* __restrict__ bs,
                         float* __restrict__ q, __half2* __restrict__ kv,
                         float* __restrict__ s, int n)
{
    constexpr int FOURC = 4 * C;
    constexpr int P  = FIN + 16;
    constexpr int KT = FIN / 32;
    constexpr int NT = FOURC / 16;
    __shared__ _Float16 wsh[FOURC * P] __attribute__((aligned(16)));
    __shared__ float bsh[FOURC];

    for (int i = threadIdx.x; i < FOURC * FIN; i += 256) {
        int col = i / FIN, f = i - (i / FIN) * FIN;
        float w;
        if (col < C)          w = Wq[f * C + col];
        else if (col < 2 * C) w = Ws[f * C + col - C];
        else if (col < 3 * C) w = Wk[f * C + col - 2 * C];
        else                  w = Wv[f * C + col - 3 * C];
        wsh[col * P + f] = (_Float16)w;
    }
    for (int i = threadIdx.x; i < FOURC; i += 256) {
        bsh[i] = (i < C) ? bq[i] : (i < 2 * C) ? bs[i - C]
               : (i < 3 * C) ? bk[i - 2 * C] : bv[i - 3 * C];
    }
    __syncthreads();

    const int lane = threadIdx.x & 63;
    const int wid  = threadIdx.x >> 6;
    const int m = lane & 15, g = lane >> 4;

    half8 bfrag[KT][NT];
    #pragma unroll
    for (int kt = 0; kt < KT; ++kt)
        #pragma unroll
        for (int nt = 0; nt < NT; ++nt)
            bfrag[kt][nt] = *reinterpret_cast<const half8*>(
                &wsh[(nt * 16 + m) * P + kt * 32 + g * 8]);

    const int tiles = n >> 4;   // N divisible by 16
    for (int t = blockIdx.x * 4 + wid; t < tiles; t += gridDim.x * 4) {
        const int row0 = t * 16;
        const float* xr = X + (size_t)(row0 + m) * FIN + g * 8;
        half8 afrag[KT];
        #pragma unroll
        for (int kt = 0; kt < KT; ++kt) {
            float4 u = *reinterpret_cast<const float4*>(xr + kt * 32);
            float4 w = *reinterpret_cast<const float4*>(xr + kt * 32 + 4);
            afrag[kt] = half8{(_Float16)u.x, (_Float16)u.y, (_Float16)u.z, (_Float16)u.w,
                              (_Float16)w.x, (_Float16)w.y, (_Float16)w.z, (_Float16)w.w};
        }
        #pragma unroll
        for (int nt = 0; nt < 2 * C / 16; ++nt) {
            f32x4 acc = {0.f, 0.f, 0.f, 0.f};
            #pragma unroll
            for (int kt = 0; kt < KT; ++kt)
                acc = __builtin_amdgcn_mfma_f32_16x16x32_f16(afrag[kt], bfrag[kt][nt], acc, 0, 0, 0);
            const int col = nt * 16 + m;
            const float bias = bsh[col];
            float* outp = (nt < C / 16) ? q : s;
            const int cc = (nt < C / 16) ? col : col - C;
            #pragma unroll
            for (int r = 0; r < 4; ++r)
                outp[(size_t)(row0 + g * 4 + r) * C + cc] = acc[r] + bias;
        }
        #pragma unroll
        for (int t2 = 0; t2 < C / 16; ++t2) {
            const int ntK = 2 * C / 16 + t2, ntV = 3 * C / 16 + t2;
            f32x4 aK = {0.f, 0.f, 0.f, 0.f}, aV = {0.f, 0.f, 0.f, 0.f};
            #pragma unroll
            for (int kt = 0; kt < KT; ++kt) {
                aK = __builtin_amdgcn_mfma_f32_16x16x32_f16(afrag[kt], bfrag[kt][ntK], aK, 0, 0, 0);
                aV = __builtin_amdgcn_mfma_f32_16x16x32_f16(afrag[kt], bfrag[kt][ntV], aV, 0, 0, 0);
            }
            const int ck = t2 * 16 + m;
            const float bK = bsh[2 * C + ck], bV = bsh[3 * C + ck];
            #pragma unroll
            for (int r = 0; r < 4; ++r)
                kv[(size_t)(row0 + g * 4 + r) * C + ck] = __floats2half2_rn(aK[r] + bK, aV[r] + bV);
        }
    }
}

// ---------- fc1 via MFMA: fp32 out + ELU ----------
template<int FIN, int COUT>
__global__ __launch_bounds__(256, 2)
void linear_mfma_kernel(const float* __restrict__ X, const float* __restrict__ W,
                        const float* __restrict__ b, float* __restrict__ out, int n)
{
    constexpr int P  = FIN + 16;
    constexpr int KT = FIN / 32;
    constexpr int NT = COUT / 16;
    __shared__ _Float16 wsh[COUT * P] __attribute__((aligned(16)));
    __shared__ float bsh[COUT];
    for (int i = threadIdx.x; i < COUT * FIN; i += 256) {
        int col = i / FIN, f = i - (i / FIN) * FIN;
        wsh[col * P + f] = (_Float16)W[f * COUT + col];
    }
    for (int i = threadIdx.x; i < COUT; i += 256) bsh[i] = b[i];
    __syncthreads();

    const int lane = threadIdx.x & 63;
    const int wid  = threadIdx.x >> 6;
    const int m = lane & 15, g = lane >> 4;

    half8 bfrag[KT][NT];
    #pragma unroll
    for (int kt = 0; kt < KT; ++kt)
        #pragma unroll
        for (int nt = 0; nt < NT; ++nt)
            bfrag[kt][nt] = *reinterpret_cast<const half8*>(
                &wsh[(nt * 16 + m) * P + kt * 32 + g * 8]);

    const int tiles = n >> 4;
    for (int t = blockIdx.x * 4 + wid; t < tiles; t += gridDim.x * 4) {
        const int row0 = t * 16;
        const float* xr = X + (size_t)(row0 + m) * FIN + g * 8;
        half8 afrag[KT];
        #pragma unroll
        for (int kt = 0; kt < KT; ++kt) {
            float4 u = *reinterpret_cast<const float4*>(xr + kt * 32);
            float4 w = *reinterpret_cast<const float4*>(xr + kt * 32 + 4);
            afrag[kt] = half8{(_Float16)u.x, (_Float16)u.y, (_Float16)u.z, (_Float16)u.w,
                              (_Float16)w.x, (_Float16)w.y, (_Float16)w.z, (_Float16)w.w};
        }
        #pragma unroll
        for (int nt = 0; nt < NT; ++nt) {
            f32x4 acc = {0.f, 0.f, 0.f, 0.f};
            #pragma unroll
            for (int kt = 0; kt < KT; ++kt)
                acc = __builtin_amdgcn_mfma_f32_16x16x32_f16(afrag[kt], bfrag[kt][nt], acc, 0, 0, 0);
            const int col = nt * 16 + m;
            const float bias = bsh[col];
            #pragma unroll
            for (int r = 0; r < 4; ++r) {
                float hv = acc[r] + bias;
                hv = (hv > 0.f) ? hv : expm1f(hv);
                out[(size_t)(row0 + g * 4 + r) * COUT + col] = hv;
            }
        }
    }
}

// ---------- fused conv: 2 ch/lane, factored e-term, masked unroll ----------
template<int C>
__global__ __launch_bounds__(256)
void conv_fused_kernel(const int* __restrict__ rowptr, const int2* __restrict__ ecsr,
                       const float* __restrict__ q, const __half2* __restrict__ kv,
                       const float* __restrict__ sres,
                       const float* __restrict__ We, const float* __restrict__ be,
                       float* __restrict__ h, float scale, int n)
{
    constexpr int LPE    = C / 2;             // lanes per edge (32 or 16)
    constexpr int EPI    = 64 / LPE;          // edge slots per wave (2 or 4)
    constexpr int LOG    = (C == 64) ? 5 : 4; // log2(LPE)
    constexpr int UNROLL = 4;
    const int wave = threadIdx.x >> 6;
    const int lane = threadIdx.x & 63;
    const int l    = lane & (LPE - 1);
    const int slot = lane >> LOG;
    const int c0   = 2 * l;
    const int node = blockIdx.x * 4 + wave;
    if (node >= n) return;

    const float2 wec = *reinterpret_cast<const float2*>(We + c0);
    const float2 bec = *reinterpret_cast<const float2*>(be + c0);
    const float2 qp  = *reinterpret_cast<const float2*>(q + (size_t)node * C + c0);
    const int r0 = rowptr[node], r1 = rowptr[node + 1];

    // per-node scalars: d1 = q.We, d0 = q.be (reduced over LPE lanes)
    float pd1 = fmaf(qp.x, wec.x, qp.y * wec.y);
    float pd0 = fmaf(qp.x, bec.x, qp.y * bec.y);
    #pragma unroll
    for (int off = LPE >> 1; off > 0; off >>= 1) {
        pd1 += __shfl_xor(pd1, off);
        pd0 += __shfl_xor(pd0, off);
    }
    const float sd1 = pd1 * scale, sd0 = pd0 * scale;

    float ssum = 0.f, swea = 0.f, a0 = 0.f, a1 = 0.f;
    const int j0 = r0 + slot;
    const int iters = (r1 - j0 + EPI - 1) / EPI;   // <=0 when no edges for slot
    for (int it = 0; it < iters; it += UNROLL) {
        int2 epk[UNROLL]; float2 kvr[UNROLL]; bool ok[UNROLL];
        #pragma unroll
        for (int u = 0; u < UNROLL; ++u) {
            int j = j0 + (it + u) * EPI;
            ok[u] = j < r1;
            epk[u] = ecsr[ok[u] ? j : r0];
        }
        #pragma unroll
        for (int u = 0; u < UNROLL; ++u)
            kvr[u] = *reinterpret_cast<const float2*>(kv + (size_t)epk[u].x * C + c0);
        #pragma unroll
        for (int u = 0; u < UNROLL; ++u) {
            float ea = __int_as_float(epk[u].y);
            float2 f0 = __half22float2(*reinterpret_cast<__half2*>(&kvr[u].x)); // k0,v0
            float2 f1 = __half22float2(*reinterpret_cast<__half2*>(&kvr[u].y)); // k1,v1
            float p = fmaf(qp.x, f0.x, qp.y * f1.x);
            #pragma unroll
            for (int off = LPE >> 1; off > 0; off >>= 1) p += __shfl_xor(p, off);
            float w = __expf(fmaf(scale, p, fmaf(sd1, ea, sd0)));
            w = ok[u] ? w : 0.f;
            ssum += w;
            swea = fmaf(w, ea, swea);
            a0 = fmaf(w, f0.y, a0);
            a1 = fmaf(w, f1.y, a1);
        }
    }

    // merge the EPI slot streams (plain sums — no max)
    #pragma unroll
    for (int off = LPE; off < 64; off <<= 1) {
        ssum += __shfl_xor(ssum, off);
        swea += __shfl_xor(swea, off);
        a0   += __shfl_xor(a0, off);
        a1   += __shfl_xor(a1, off);
    }

    if (slot == 0) {
        float inv = 1.f / (ssum + 1e-16f);
        // out_c = inv*(acc_c + We_c*swea + be_c*ssum)
        float t0 = fmaf(wec.x, swea, fmaf(bec.x, ssum, a0));
        float t1 = fmaf(wec.y, swea, fmaf(bec.y, ssum, a1));
        float2 sr = *reinterpret_cast<const float2*>(sres + (size_t)node * C + c0);
        float h0 = fmaf(t0, inv, sr.x);
        float h1 = fmaf(t1, inv, sr.y);
        h0 = (h0 > 0.f) ? h0 : expm1f(h0);
        h1 = (h1 > 0.f) ? h1 : expm1f(h1);
        *reinterpret_cast<float2*>(h + (size_t)node * C + c0) = make_float2(h0, h1);
    }
}

// ---------- fc2 + log_softmax ----------
#define H1_DIM 128
#define NC_DIM 10
__global__ __launch_bounds__(256)
void head_kernel(const float* __restrict__ Hf, const float* __restrict__ W,
                 const float* __restrict__ b, float* __restrict__ out, int n)
{
    __shared__ float wsh[H1_DIM * NC_DIM];
    __shared__ float bsh[NC_DIM];
    for (int i = threadIdx.x; i < H1_DIM * NC_DIM; i += 256) wsh[i] = W[i];
    for (int i = threadIdx.x; i < NC_DIM; i += 256) bsh[i] = b[i];
    __syncthreads();
    for (int row = blockIdx.x * 256 + threadIdx.x; row < n; row += gridDim.x * 256) {
        const float* hr = Hf + (size_t)row * H1_DIM;
        float logit[NC_DIM];
        #pragma unroll
        for (int c = 0; c < NC_DIM; ++c) logit[c] = bsh[c];
        for (int f = 0; f < H1_DIM; ++f) {
            float xv = hr[f];
            #pragma unroll
            for (int c = 0; c < NC_DIM; ++c) logit[c] = fmaf(xv, wsh[f * NC_DIM + c], logit[c]);
        }
        float m = logit[0];
        #pragma unroll
        for (int c = 1; c < NC_DIM; ++c) m = fmaxf(m, logit[c]);
        float sum = 0.f;
        #pragma unroll
        for (int c = 0; c < NC_DIM; ++c) sum += __expf(logit[c] - m);
        float lse = m + logf(sum);
        #pragma unroll
        for (int c = 0; c < NC_DIM; ++c) out[(size_t)row * NC_DIM + c] = logit[c] - lse;
    }
}

extern "C" void kernel_launch(void* const* d_in, const int* in_sizes, int n_in,
                              void* d_out, int out_size, void* d_ws, size_t ws_size,
                              hipStream_t stream) {
    const float* x   = (const float*)d_in[0];
    const int*   ei  = (const int*)d_in[1];
    const float* ea  = (const float*)d_in[2];
    const float *Wq1 = (const float*)d_in[3],  *bq1 = (const float*)d_in[4];
    const float *Wk1 = (const float*)d_in[5],  *bk1 = (const float*)d_in[6];
    const float *Wv1 = (const float*)d_in[7],  *bv1 = (const float*)d_in[8];
    const float *We1 = (const float*)d_in[9],  *be1 = (const float*)d_in[10];
    const float *Ws1 = (const float*)d_in[11], *bs1 = (const float*)d_in[12];
    const float *Wq2 = (const float*)d_in[13], *bq2 = (const float*)d_in[14];
    const float *Wk2 = (const float*)d_in[15], *bk2 = (const float*)d_in[16];
    const float *Wv2 = (const float*)d_in[17], *bv2 = (const float*)d_in[18];
    const float *We2 = (const float*)d_in[19], *be2 = (const float*)d_in[20];
    const float *Ws2 = (const float*)d_in[21], *bs2 = (const float*)d_in[22];
    const float *Wf1 = (const float*)d_in[23], *bf1 = (const float*)d_in[24];
    const float *Wf2 = (const float*)d_in[25], *bf2 = (const float*)d_in[26];

    const int N = in_sizes[0] / 64;   // 100000
    const int E = in_sizes[2];        // 1600000
    const int* src = ei;              // edge_index[0]
    const int* dst = ei + E;          // edge_index[1]

    float* wsf = (float*)d_ws;
    const size_t N64 = (size_t)N * 64;
    float* q      = wsf;                      // N*64
    __half2* kv   = (__half2*)(q + N64);      // N*64 half2 (k,v packed)
    float* s      = (float*)(kv + N64);       // N*64 (skip proj)
    float* h1     = s + N64;                  // N*32
    float* h2     = h1 + (size_t)N * 32;      // N*64
    int* deg      = (int*)(h2 + N64);         // N
    int* rowptr   = deg + N;                  // N+1
    int* bsum     = rowptr + N + 1;           // SCAN_NB
    int* boff     = bsum + SCAN_NB;           // SCAN_NB
    int* rank     = boff + SCAN_NB;           // E
    int2* ecsr    = (int2*)(rank + E);        // E (packed {src, eattr})
    float* hfc    = wsf;                      // N*128 (reuses dead q after conv2)

    float* out = (float*)d_out;

    // ---- CSR build ----
    hipMemsetAsync(deg, 0, (size_t)N * 4, stream);
    count_rank_kernel<<<2048, 256, 0, stream>>>(dst, deg, rank, E);
    blocksum_kernel<<<SCAN_NB, 256, 0, stream>>>(deg, bsum, N);
    scanb_kernel<<<1, 256, 0, stream>>>(bsum, boff, rowptr + N, SCAN_NB);
    writeptr_kernel<<<SCAN_NB, 256, 0, stream>>>(deg, boff, rowptr, N);
    fill_pack_kernel<<<4096, 256, 0, stream>>>(src, dst, ea, rowptr, rank, ecsr, E);

    const int convGrid = (N + 3) / 4;

    // ---- layer 1 (C=32) ----
    linear4_mfma_kernel<64, 32><<<1024, 256, 0, stream>>>(
        x, Wq1, bq1, Wk1, bk1, Wv1, bv1, Ws1, bs1, q, kv, s, N);
    conv_fused_kernel<32><<<convGrid, 256, 0, stream>>>(
        rowptr, ecsr, q, kv, s, We1, be1, h1, 0.17677669529663687f, N);

    // ---- layer 2 (C=64) ----
    linear4_mfma_kernel<32, 64><<<1024, 256, 0, stream>>>(
        h1, Wq2, bq2, Wk2, bk2, Wv2, bv2, Ws2, bs2, q, kv, s, N);
    conv_fused_kernel<64><<<convGrid, 256, 0, stream>>>(
        rowptr, ecsr, q, kv, s, We2, be2, h2, 0.125f, N);

    // ---- MLP head ----
    linear_mfma_kernel<64, 128><<<1024, 256, 0, stream>>>(h2, Wf1, bf1, hfc, N);
    head_kernel<<<512, 256, 0, stream>>>(hfc, Wf2, bf2, out, N);
}

// Round 14
// 337.719 us; speedup vs baseline: 1.1007x; 1.0385x over previous
//
#include <hip/hip_runtime.h>
#include <hip/hip_fp16.h>
#include <math.h>

// TransformerConvNet: 2x TransformerConv(heads=1) + ELU + MLP head + log_softmax
// N=100000 nodes, E=1600000 edges, F_IN=64, C1=32, C2=64, H1=128, NC=10
//
// R14: conv_fused = 4 ch/lane + factored e-term + masked unroll (R12 geometry
// with R13's fixes). Reduce is 4 steps (C=64) / 3 steps (C=32), all
// DPP-eligible offsets. CSR build + MFMA linears unchanged.

#define SCAN_NB 256

typedef _Float16 half8 __attribute__((ext_vector_type(8)));
typedef float f32x4 __attribute__((ext_vector_type(4)));

// ---------- CSR build ----------
__global__ __launch_bounds__(256)
void count_rank_kernel(const int* __restrict__ dst, int* __restrict__ deg,
                       int* __restrict__ rank, int e) {
    for (int i = blockIdx.x * 256 + threadIdx.x; i < e; i += gridDim.x * 256)
        rank[i] = atomicAdd(deg + dst[i], 1);
}

__global__ __launch_bounds__(256)
void blocksum_kernel(const int* __restrict__ deg, int* __restrict__ bsum, int n) {
    __shared__ int ls[256];
    const int chunk = (n + gridDim.x - 1) / gridDim.x;
    const int b0 = blockIdx.x * chunk;
    const int b1 = (b0 + chunk < n) ? b0 + chunk : n;
    int s = 0;
    for (int i = b0 + threadIdx.x; i < b1; i += 256) s += deg[i];
    ls[threadIdx.x] = s;
    __syncthreads();
    for (int off = 128; off > 0; off >>= 1) {
        if (threadIdx.x < off) ls[threadIdx.x] += ls[threadIdx.x + off];
        __syncthreads();
    }
    if (threadIdx.x == 0) bsum[blockIdx.x] = ls[0];
}

__global__ __launch_bounds__(256)
void scanb_kernel(const int* __restrict__ bsum, int* __restrict__ boff,
                  int* __restrict__ total, int nb) {
    __shared__ int ls[256];
    const int t = threadIdx.x;
    int v = (t < nb) ? bsum[t] : 0;
    ls[t] = v;
    __syncthreads();
    for (int off = 1; off < 256; off <<= 1) {
        int u = (t >= off) ? ls[t - off] : 0;
        __syncthreads();
        ls[t] += u;
        __syncthreads();
    }
    if (t < nb) boff[t] = ls[t] - v;
    if (t == 255) *total = ls[255];
}

__global__ __launch_bounds__(256)
void writeptr_kernel(const int* __restrict__ deg, const int* __restrict__ boff,
                     int* __restrict__ rowptr, int n) {
    __shared__ int ls[256];
    const int chunk = (n + gridDim.x - 1) / gridDim.x;
    const int b0 = blockIdx.x * chunk;
    const int b1 = (b0 + chunk < n) ? b0 + chunk : n;
    const int tchunk = (chunk + 255) / 256;
    const int t0 = b0 + threadIdx.x * tchunk;
    const int t1 = (t0 + tchunk < b1) ? t0 + tchunk : b1;
    int s = 0;
    for (int i = t0; i < t1; ++i) s += deg[i];
    ls[threadIdx.x] = s;
    __syncthreads();
    for (int off = 1; off < 256; off <<= 1) {
        int u = (threadIdx.x >= off) ? ls[threadIdx.x - off] : 0;
        __syncthreads();
        ls[threadIdx.x] += u;
        __syncthreads();
    }
    int run = boff[blockIdx.x] + ls[threadIdx.x] - s;
    for (int i = t0; i < t1; ++i) { rowptr[i] = run; run += deg[i]; }
}

__global__ __launch_bounds__(256)
void fill_pack_kernel(const int* __restrict__ src, const int* __restrict__ dst,
                      const float* __restrict__ eattr,
                      const int* __restrict__ rowptr, const int* __restrict__ rank,
                      int2* __restrict__ ecsr, int e) {
    for (int i = blockIdx.x * 256 + threadIdx.x; i < e; i += gridDim.x * 256) {
        int p = rowptr[dst[i]] + rank[i];
        ecsr[p] = make_int2(src[i], __float_as_int(eattr[i]));
    }
}

// ---------- linear4 via MFMA: q | s (fp32) + kv (__half2) ----------
template<int FIN, int C>
__global__ __launch_bounds__(256, 2)
void linear4_mfma_kernel(const float* __restrict__ X,
                         const float* __restrict__ Wq, const float* __restrict__ bq,
                         const float* __restrict__ Wk, const float* __restrict__ bk,
                         const float* __restrict__ Wv, const float* __restrict__ bv,
                         const float* __restrict__ Ws, const float* __restrict__ bs,
                         float* __restrict__ q, __half2* __restrict__ kv,
                         float* __restrict__ s, int n)
{
    constexpr int FOURC = 4 * C;
    constexpr int P  = FIN + 16;
    constexpr int KT = FIN / 32;
    constexpr int NT = FOURC / 16;
    __shared__ _Float16 wsh[FOURC * P] __attribute__((aligned(16)));
    __shared__ float bsh[FOURC];

    for (int i = threadIdx.x; i < FOURC * FIN; i += 256) {
        int col = i / FIN, f = i - (i / FIN) * FIN;
        float w;
        if (col < C)          w = Wq[f * C + col];
        else if (col < 2 * C) w = Ws[f * C + col - C];
        else if (col < 3 * C) w = Wk[f * C + col - 2 * C];
        else                  w = Wv[f * C + col - 3 * C];
        wsh[col * P + f] = (_Float16)w;
    }
    for (int i = threadIdx.x; i < FOURC; i += 256) {
        bsh[i] = (i < C) ? bq[i] : (i < 2 * C) ? bs[i - C]
               : (i < 3 * C) ? bk[i - 2 * C] : bv[i - 3 * C];
    }
    __syncthreads();

    const int lane = threadIdx.x & 63;
    const int wid  = threadIdx.x >> 6;
    const int m = lane & 15, g = lane >> 4;

    half8 bfrag[KT][NT];
    #pragma unroll
    for (int kt = 0; kt < KT; ++kt)
        #pragma unroll
        for (int nt = 0; nt < NT; ++nt)
            bfrag[kt][nt] = *reinterpret_cast<const half8*>(
                &wsh[(nt * 16 + m) * P + kt * 32 + g * 8]);

    const int tiles = n >> 4;   // N divisible by 16
    for (int t = blockIdx.x * 4 + wid; t < tiles; t += gridDim.x * 4) {
        const int row0 = t * 16;
        const float* xr = X + (size_t)(row0 + m) * FIN + g * 8;
        half8 afrag[KT];
        #pragma unroll
        for (int kt = 0; kt < KT; ++kt) {
            float4 u = *reinterpret_cast<const float4*>(xr + kt * 32);
            float4 w = *reinterpret_cast<const float4*>(xr + kt * 32 + 4);
            afrag[kt] = half8{(_Float16)u.x, (_Float16)u.y, (_Float16)u.z, (_Float16)u.w,
                              (_Float16)w.x, (_Float16)w.y, (_Float16)w.z, (_Float16)w.w};
        }
        #pragma unroll
        for (int nt = 0; nt < 2 * C / 16; ++nt) {
            f32x4 acc = {0.f, 0.f, 0.f, 0.f};
            #pragma unroll
            for (int kt = 0; kt < KT; ++kt)
                acc = __builtin_amdgcn_mfma_f32_16x16x32_f16(afrag[kt], bfrag[kt][nt], acc, 0, 0, 0);
            const int col = nt * 16 + m;
            const float bias = bsh[col];
            float* outp = (nt < C / 16) ? q : s;
            const int cc = (nt < C / 16) ? col : col - C;
            #pragma unroll
            for (int r = 0; r < 4; ++r)
                outp[(size_t)(row0 + g * 4 + r) * C + cc] = acc[r] + bias;
        }
        #pragma unroll
        for (int t2 = 0; t2 < C / 16; ++t2) {
            const int ntK = 2 * C / 16 + t2, ntV = 3 * C / 16 + t2;
            f32x4 aK = {0.f, 0.f, 0.f, 0.f}, aV = {0.f, 0.f, 0.f, 0.f};
            #pragma unroll
            for (int kt = 0; kt < KT; ++kt) {
                aK = __builtin_amdgcn_mfma_f32_16x16x32_f16(afrag[kt], bfrag[kt][ntK], aK, 0, 0, 0);
                aV = __builtin_amdgcn_mfma_f32_16x16x32_f16(afrag[kt], bfrag[kt][ntV], aV, 0, 0, 0);
            }
            const int ck = t2 * 16 + m;
            const float bK = bsh[2 * C + ck], bV = bsh[3 * C + ck];
            #pragma unroll
            for (int r = 0; r < 4; ++r)
                kv[(size_t)(row0 + g * 4 + r) * C + ck] = __floats2half2_rn(aK[r] + bK, aV[r] + bV);
        }
    }
}

// ---------- fc1 via MFMA: fp32 out + ELU ----------
template<int FIN, int COUT>
__global__ __launch_bounds__(256, 2)
void linear_mfma_kernel(const float* __restrict__ X, const float* __restrict__ W,
                        const float* __restrict__ b, float* __restrict__ out, int n)
{
    constexpr int P  = FIN + 16;
    constexpr int KT = FIN / 32;
    constexpr int NT = COUT / 16;
    __shared__ _Float16 wsh[COUT * P] __attribute__((aligned(16)));
    __shared__ float bsh[COUT];
    for (int i = threadIdx.x; i < COUT * FIN; i += 256) {
        int col = i / FIN, f = i - (i / FIN) * FIN;
        wsh[col * P + f] = (_Float16)W[f * COUT + col];
    }
    for (int i = threadIdx.x; i < COUT; i += 256) bsh[i] = b[i];
    __syncthreads();

    const int lane = threadIdx.x & 63;
    const int wid  = threadIdx.x >> 6;
    const int m = lane & 15, g = lane >> 4;

    half8 bfrag[KT][NT];
    #pragma unroll
    for (int kt = 0; kt < KT; ++kt)
        #pragma unroll
        for (int nt = 0; nt < NT; ++nt)
            bfrag[kt][nt] = *reinterpret_cast<const half8*>(
                &wsh[(nt * 16 + m) * P + kt * 32 + g * 8]);

    const int tiles = n >> 4;
    for (int t = blockIdx.x * 4 + wid; t < tiles; t += gridDim.x * 4) {
        const int row0 = t * 16;
        const float* xr = X + (size_t)(row0 + m) * FIN + g * 8;
        half8 afrag[KT];
        #pragma unroll
        for (int kt = 0; kt < KT; ++kt) {
            float4 u = *reinterpret_cast<const float4*>(xr + kt * 32);
            float4 w = *reinterpret_cast<const float4*>(xr + kt * 32 + 4);
            afrag[kt] = half8{(_Float16)u.x, (_Float16)u.y, (_Float16)u.z, (_Float16)u.w,
                              (_Float16)w.x, (_Float16)w.y, (_Float16)w.z, (_Float16)w.w};
        }
        #pragma unroll
        for (int nt = 0; nt < NT; ++nt) {
            f32x4 acc = {0.f, 0.f, 0.f, 0.f};
            #pragma unroll
            for (int kt = 0; kt < KT; ++kt)
                acc = __builtin_amdgcn_mfma_f32_16x16x32_f16(afrag[kt], bfrag[kt][nt], acc, 0, 0, 0);
            const int col = nt * 16 + m;
            const float bias = bsh[col];
            #pragma unroll
            for (int r = 0; r < 4; ++r) {
                float hv = acc[r] + bias;
                hv = (hv > 0.f) ? hv : expm1f(hv);
                out[(size_t)(row0 + g * 4 + r) * COUT + col] = hv;
            }
        }
    }
}

// ---------- fused conv: 4 ch/lane, factored e-term, masked unroll ----------
template<int C>
__global__ __launch_bounds__(256)
void conv_fused_kernel(const int* __restrict__ rowptr, const int2* __restrict__ ecsr,
                       const float* __restrict__ q, const __half2* __restrict__ kv,
                       const float* __restrict__ sres,
                       const float* __restrict__ We, const float* __restrict__ be,
                       float* __restrict__ h, float scale, int n)
{
    constexpr int LPE    = C / 4;             // lanes per edge (16 or 8)
    constexpr int EPI    = 64 / LPE;          // edge slots per wave (4 or 8)
    constexpr int LOG    = (C == 64) ? 4 : 3; // log2(LPE)
    constexpr int UNROLL = (C == 64) ? 4 : 2;
    const int wave = threadIdx.x >> 6;
    const int lane = threadIdx.x & 63;
    const int l    = lane & (LPE - 1);
    const int slot = lane >> LOG;
    const int c0   = 4 * l;
    const int node = blockIdx.x * 4 + wave;
    if (node >= n) return;

    const float4 wec = *reinterpret_cast<const float4*>(We + c0);
    const float4 bec = *reinterpret_cast<const float4*>(be + c0);
    const float4 qp  = *reinterpret_cast<const float4*>(q + (size_t)node * C + c0);
    const int r0 = rowptr[node], r1 = rowptr[node + 1];

    // per-node scalars d1 = q.We, d0 = q.be (reduced over LPE lanes)
    float pd1 = fmaf(qp.x, wec.x, fmaf(qp.y, wec.y, fmaf(qp.z, wec.z, qp.w * wec.w)));
    float pd0 = fmaf(qp.x, bec.x, fmaf(qp.y, bec.y, fmaf(qp.z, bec.z, qp.w * bec.w)));
    #pragma unroll
    for (int off = LPE >> 1; off > 0; off >>= 1) {
        pd1 += __shfl_xor(pd1, off);
        pd0 += __shfl_xor(pd0, off);
    }
    const float sd1 = pd1 * scale, sd0 = pd0 * scale;

    float ssum = 0.f, swea = 0.f;
    float a0 = 0.f, a1 = 0.f, a2 = 0.f, a3 = 0.f;
    const int j0 = r0 + slot;
    const int iters = (r1 - j0 + EPI - 1) / EPI;   // <=0 when no edges for slot
    for (int it = 0; it < iters; it += UNROLL) {
        int2 epk[UNROLL]; float4 kvr[UNROLL]; bool ok[UNROLL];
        #pragma unroll
        for (int u = 0; u < UNROLL; ++u) {
            int j = j0 + (it + u) * EPI;
            ok[u] = j < r1;
            epk[u] = ecsr[ok[u] ? j : r0];
        }
        #pragma unroll
        for (int u = 0; u < UNROLL; ++u)
            kvr[u] = *reinterpret_cast<const float4*>(kv + (size_t)epk[u].x * C + c0);
        #pragma unroll
        for (int u = 0; u < UNROLL; ++u) {
            float ea = __int_as_float(epk[u].y);
            float2 f0 = __half22float2(*reinterpret_cast<__half2*>(&kvr[u].x)); // k0,v0
            float2 f1 = __half22float2(*reinterpret_cast<__half2*>(&kvr[u].y));
            float2 f2 = __half22float2(*reinterpret_cast<__half2*>(&kvr[u].z));
            float2 f3 = __half22float2(*reinterpret_cast<__half2*>(&kvr[u].w));
            float p = fmaf(qp.x, f0.x, fmaf(qp.y, f1.x, fmaf(qp.z, f2.x, qp.w * f3.x)));
            #pragma unroll
            for (int off = LPE >> 1; off > 0; off >>= 1) p += __shfl_xor(p, off);
            float w = __expf(fmaf(scale, p, fmaf(sd1, ea, sd0)));
            w = ok[u] ? w : 0.f;
            ssum += w;
            swea = fmaf(w, ea, swea);
            a0 = fmaf(w, f0.y, a0);
            a1 = fmaf(w, f1.y, a1);
            a2 = fmaf(w, f2.y, a2);
            a3 = fmaf(w, f3.y, a3);
        }
    }

    // merge the EPI slot streams (plain sums — no max)
    #pragma unroll
    for (int off = LPE; off < 64; off <<= 1) {
        ssum += __shfl_xor(ssum, off);
        swea += __shfl_xor(swea, off);
        a0   += __shfl_xor(a0, off);
        a1   += __shfl_xor(a1, off);
        a2   += __shfl_xor(a2, off);
        a3   += __shfl_xor(a3, off);
    }

    if (slot == 0) {
        float inv = 1.f / (ssum + 1e-16f);
        float t0 = fmaf(wec.x, swea, fmaf(bec.x, ssum, a0));
        float t1 = fmaf(wec.y, swea, fmaf(bec.y, ssum, a1));
        float t2 = fmaf(wec.z, swea, fmaf(bec.z, ssum, a2));
        float t3 = fmaf(wec.w, swea, fmaf(bec.w, ssum, a3));
        float4 sr = *reinterpret_cast<const float4*>(sres + (size_t)node * C + c0);
        float h0 = fmaf(t0, inv, sr.x);
        float h1 = fmaf(t1, inv, sr.y);
        float h2v = fmaf(t2, inv, sr.z);
        float h3 = fmaf(t3, inv, sr.w);
        h0 = (h0 > 0.f) ? h0 : expm1f(h0);
        h1 = (h1 > 0.f) ? h1 : expm1f(h1);
        h2v = (h2v > 0.f) ? h2v : expm1f(h2v);
        h3 = (h3 > 0.f) ? h3 : expm1f(h3);
        *reinterpret_cast<float4*>(h + (size_t)node * C + c0) = make_float4(h0, h1, h2v, h3);
    }
}

// ---------- fc2 + log_softmax ----------
#define H1_DIM 128
#define NC_DIM 10
__global__ __launch_bounds__(256)
void head_kernel(const float* __restrict__ Hf, const float* __restrict__ W,
                 const float* __restrict__ b, float* __restrict__ out, int n)
{
    __shared__ float wsh[H1_DIM * NC_DIM];
    __shared__ float bsh[NC_DIM];
    for (int i = threadIdx.x; i < H1_DIM * NC_DIM; i += 256) wsh[i] = W[i];
    for (int i = threadIdx.x; i < NC_DIM; i += 256) bsh[i] = b[i];
    __syncthreads();
    for (int row = blockIdx.x * 256 + threadIdx.x; row < n; row += gridDim.x * 256) {
        const float* hr = Hf + (size_t)row * H1_DIM;
        float logit[NC_DIM];
        #pragma unroll
        for (int c = 0; c < NC_DIM; ++c) logit[c] = bsh[c];
        for (int f = 0; f < H1_DIM; ++f) {
            float xv = hr[f];
            #pragma unroll
            for (int c = 0; c < NC_DIM; ++c) logit[c] = fmaf(xv, wsh[f * NC_DIM + c], logit[c]);
        }
        float m = logit[0];
        #pragma unroll
        for (int c = 1; c < NC_DIM; ++c) m = fmaxf(m, logit[c]);
        float sum = 0.f;
        #pragma unroll
        for (int c = 0; c < NC_DIM; ++c) sum += __expf(logit[c] - m);
        float lse = m + logf(sum);
        #pragma unroll
        for (int c = 0; c < NC_DIM; ++c) out[(size_t)row * NC_DIM + c] = logit[c] - lse;
    }
}

extern "C" void kernel_launch(void* const* d_in, const int* in_sizes, int n_in,
                              void* d_out, int out_size, void* d_ws, size_t ws_size,
                              hipStream_t stream) {
    const float* x   = (const float*)d_in[0];
    const int*   ei  = (const int*)d_in[1];
    const float* ea  = (const float*)d_in[2];
    const float *Wq1 = (const float*)d_in[3],  *bq1 = (const float*)d_in[4];
    const float *Wk1 = (const float*)d_in[5],  *bk1 = (const float*)d_in[6];
    const float *Wv1 = (const float*)d_in[7],  *bv1 = (const float*)d_in[8];
    const float *We1 = (const float*)d_in[9],  *be1 = (const float*)d_in[10];
    const float *Ws1 = (const float*)d_in[11], *bs1 = (const float*)d_in[12];
    const float *Wq2 = (const float*)d_in[13], *bq2 = (const float*)d_in[14];
    const float *Wk2 = (const float*)d_in[15], *bk2 = (const float*)d_in[16];
    const float *Wv2 = (const float*)d_in[17], *bv2 = (const float*)d_in[18];
    const float *We2 = (const float*)d_in[19], *be2 = (const float*)d_in[20];
    const float *Ws2 = (const float*)d_in[21], *bs2 = (const float*)d_in[22];
    const float *Wf1 = (const float*)d_in[23], *bf1 = (const float*)d_in[24];
    const float *Wf2 = (const float*)d_in[25], *bf2 = (const float*)d_in[26];

    const int N = in_sizes[0] / 64;   // 100000
    const int E = in_sizes[2];        // 1600000
    const int* src = ei;              // edge_index[0]
    const int* dst = ei + E;          // edge_index[1]

    float* wsf = (float*)d_ws;
    const size_t N64 = (size_t)N * 64;
    float* q      = wsf;                      // N*64
    __half2* kv   = (__half2*)(q + N64);      // N*64 half2 (k,v packed)
    float* s      = (float*)(kv + N64);       // N*64 (skip proj)
    float* h1     = s + N64;                  // N*32
    float* h2     = h1 + (size_t)N * 32;      // N*64
    int* deg      = (int*)(h2 + N64);         // N
    int* rowptr   = deg + N;                  // N+1
    int* bsum     = rowptr + N + 1;           // SCAN_NB
    int* boff     = bsum + SCAN_NB;           // SCAN_NB
    int* rank     = boff + SCAN_NB;           // E
    int2* ecsr    = (int2*)(rank + E);        // E (packed {src, eattr})
    float* hfc    = wsf;                      // N*128 (reuses dead q after conv2)

    float* out = (float*)d_out;

    // ---- CSR build ----
    hipMemsetAsync(deg, 0, (size_t)N * 4, stream);
    count_rank_kernel<<<2048, 256, 0, stream>>>(dst, deg, rank, E);
    blocksum_kernel<<<SCAN_NB, 256, 0, stream>>>(deg, bsum, N);
    scanb_kernel<<<1, 256, 0, stream>>>(bsum, boff, rowptr + N, SCAN_NB);
    writeptr_kernel<<<SCAN_NB, 256, 0, stream>>>(deg, boff, rowptr, N);
    fill_pack_kernel<<<4096, 256, 0, stream>>>(src, dst, ea, rowptr, rank, ecsr, E);

    const int convGrid = (N + 3) / 4;

    // ---- layer 1 (C=32) ----
    linear4_mfma_kernel<64, 32><<<1024, 256, 0, stream>>>(
        x, Wq1, bq1, Wk1, bk1, Wv1, bv1, Ws1, bs1, q, kv, s, N);
    conv_fused_kernel<32><<<convGrid, 256, 0, stream>>>(
        rowptr, ecsr, q, kv, s, We1, be1, h1, 0.17677669529663687f, N);

    // ---- layer 2 (C=64) ----
    linear4_mfma_kernel<32, 64><<<1024, 256, 0, stream>>>(
        h1, Wq2, bq2, Wk2, bk2, Wv2, bv2, Ws2, bs2, q, kv, s, N);
    conv_fused_kernel<64><<<convGrid, 256, 0, stream>>>(
        rowptr, ecsr, q, kv, s, We2, be2, h2, 0.125f, N);

    // ---- MLP head ----
    linear_mfma_kernel<64, 128><<<1024, 256, 0, stream>>>(h2, Wf1, bf1, hfc, N);
    head_kernel<<<512, 256, 0, stream>>>(hfc, Wf2, bf2, out, N);
}

// Round 16
// 321.059 us; speedup vs baseline: 1.1578x; 1.0519x over previous
//
#include <hip/hip_runtime.h>
#include <hip/hip_fp16.h>
#include <math.h>

// TransformerConvNet: 2x TransformerConv(heads=1) + ELU + MLP head + log_softmax
// N=100000 nodes, E=1600000 edges, F_IN=64, C1=32, C2=64, H1=128, NC=10
//
// R15 (resubmit after infra failure): (1) fc1+fc2+log_softmax fused into one
// MFMA kernel (kills 100 MB hfc round trip); (2) count_rank overlapped with
// linear4-L1 in one role-split mega-kernel (2:1 block interleave). Convs +
// CSR scan/fill unchanged (R14).

#define SCAN_NB 256

typedef _Float16 half8 __attribute__((ext_vector_type(8)));
typedef float f32x4 __attribute__((ext_vector_type(4)));

// ---------- CSR build ----------
__global__ __launch_bounds__(256)
void blocksum_kernel(const int* __restrict__ deg, int* __restrict__ bsum, int n) {
    __shared__ int ls[256];
    const int chunk = (n + gridDim.x - 1) / gridDim.x;
    const int b0 = blockIdx.x * chunk;
    const int b1 = (b0 + chunk < n) ? b0 + chunk : n;
    int s = 0;
    for (int i = b0 + threadIdx.x; i < b1; i += 256) s += deg[i];
    ls[threadIdx.x] = s;
    __syncthreads();
    for (int off = 128; off > 0; off >>= 1) {
        if (threadIdx.x < off) ls[threadIdx.x] += ls[threadIdx.x + off];
        __syncthreads();
    }
    if (threadIdx.x == 0) bsum[blockIdx.x] = ls[0];
}

__global__ __launch_bounds__(256)
void scanb_kernel(const int* __restrict__ bsum, int* __restrict__ boff,
                  int* __restrict__ total, int nb) {
    __shared__ int ls[256];
    const int t = threadIdx.x;
    int v = (t < nb) ? bsum[t] : 0;
    ls[t] = v;
    __syncthreads();
    for (int off = 1; off < 256; off <<= 1) {
        int u = (t >= off) ? ls[t - off] : 0;
        __syncthreads();
        ls[t] += u;
        __syncthreads();
    }
    if (t < nb) boff[t] = ls[t] - v;
    if (t == 255) *total = ls[255];
}

__global__ __launch_bounds__(256)
void writeptr_kernel(const int* __restrict__ deg, const int* __restrict__ boff,
                     int* __restrict__ rowptr, int n) {
    __shared__ int ls[256];
    const int chunk = (n + gridDim.x - 1) / gridDim.x;
    const int b0 = blockIdx.x * chunk;
    const int b1 = (b0 + chunk < n) ? b0 + chunk : n;
    const int tchunk = (chunk + 255) / 256;
    const int t0 = b0 + threadIdx.x * tchunk;
    const int t1 = (t0 + tchunk < b1) ? t0 + tchunk : b1;
    int s = 0;
    for (int i = t0; i < t1; ++i) s += deg[i];
    ls[threadIdx.x] = s;
    __syncthreads();
    for (int off = 1; off < 256; off <<= 1) {
        int u = (threadIdx.x >= off) ? ls[threadIdx.x - off] : 0;
        __syncthreads();
        ls[threadIdx.x] += u;
        __syncthreads();
    }
    int run = boff[blockIdx.x] + ls[threadIdx.x] - s;
    for (int i = t0; i < t1; ++i) { rowptr[i] = run; run += deg[i]; }
}

__global__ __launch_bounds__(256)
void fill_pack_kernel(const int* __restrict__ src, const int* __restrict__ dst,
                      const float* __restrict__ eattr,
                      const int* __restrict__ rowptr, const int* __restrict__ rank,
                      int2* __restrict__ ecsr, int e) {
    for (int i = blockIdx.x * 256 + threadIdx.x; i < e; i += gridDim.x * 256) {
        int p = rowptr[dst[i]] + rank[i];
        ecsr[p] = make_int2(src[i], __float_as_int(eattr[i]));
    }
}

// ---------- fused: count_rank (blocks role<2) + linear4-L1 MFMA (role==2) ----------
#define CNT_NB 2048
#define L4_NB  1024
template<int FIN, int C>
__global__ __launch_bounds__(256, 2)
void count_linear4_kernel(const int* __restrict__ dst, int* __restrict__ deg,
                          int* __restrict__ rank, int e,
                          const float* __restrict__ X,
                          const float* __restrict__ Wq, const float* __restrict__ bq,
                          const float* __restrict__ Wk, const float* __restrict__ bk,
                          const float* __restrict__ Wv, const float* __restrict__ bv,
                          const float* __restrict__ Ws, const float* __restrict__ bs,
                          float* __restrict__ q, __half2* __restrict__ kv,
                          float* __restrict__ s, int n)
{
    constexpr int FOURC = 4 * C;
    constexpr int P  = FIN + 16;
    constexpr int KT = FIN / 32;
    constexpr int NT = FOURC / 16;
    __shared__ _Float16 wsh[FOURC * P] __attribute__((aligned(16)));
    __shared__ float bsh[FOURC];

    const int b3 = blockIdx.x / 3, role = blockIdx.x % 3;
    if (role < 2) {
        // ---- count_rank path (2048 virtual blocks) ----
        const int cb = b3 * 2 + role;
        for (int i = cb * 256 + threadIdx.x; i < e; i += CNT_NB * 256)
            rank[i] = atomicAdd(deg + dst[i], 1);
        return;
    }

    // ---- linear4 path (1024 virtual blocks) ----
    const int lb = b3;
    for (int i = threadIdx.x; i < FOURC * FIN; i += 256) {
        int col = i / FIN, f = i - (i / FIN) * FIN;
        float w;
        if (col < C)          w = Wq[f * C + col];
        else if (col < 2 * C) w = Ws[f * C + col - C];
        else if (col < 3 * C) w = Wk[f * C + col - 2 * C];
        else                  w = Wv[f * C + col - 3 * C];
        wsh[col * P + f] = (_Float16)w;
    }
    for (int i = threadIdx.x; i < FOURC; i += 256) {
        bsh[i] = (i < C) ? bq[i] : (i < 2 * C) ? bs[i - C]
               : (i < 3 * C) ? bk[i - 2 * C] : bv[i - 3 * C];
    }
    __syncthreads();

    const int lane = threadIdx.x & 63;
    const int wid  = threadIdx.x >> 6;
    const int m = lane & 15, g = lane >> 4;

    half8 bfrag[KT][NT];
    #pragma unroll
    for (int kt = 0; kt < KT; ++kt)
        #pragma unroll
        for (int nt = 0; nt < NT; ++nt)
            bfrag[kt][nt] = *reinterpret_cast<const half8*>(
                &wsh[(nt * 16 + m) * P + kt * 32 + g * 8]);

    const int tiles = n >> 4;
    for (int t = lb * 4 + wid; t < tiles; t += L4_NB * 4) {
        const int row0 = t * 16;
        const float* xr = X + (size_t)(row0 + m) * FIN + g * 8;
        half8 afrag[KT];
        #pragma unroll
        for (int kt = 0; kt < KT; ++kt) {
            float4 u = *reinterpret_cast<const float4*>(xr + kt * 32);
            float4 w = *reinterpret_cast<const float4*>(xr + kt * 32 + 4);
            afrag[kt] = half8{(_Float16)u.x, (_Float16)u.y, (_Float16)u.z, (_Float16)u.w,
                              (_Float16)w.x, (_Float16)w.y, (_Float16)w.z, (_Float16)w.w};
        }
        #pragma unroll
        for (int nt = 0; nt < 2 * C / 16; ++nt) {
            f32x4 acc = {0.f, 0.f, 0.f, 0.f};
            #pragma unroll
            for (int kt = 0; kt < KT; ++kt)
                acc = __builtin_amdgcn_mfma_f32_16x16x32_f16(afrag[kt], bfrag[kt][nt], acc, 0, 0, 0);
            const int col = nt * 16 + m;
            const float bias = bsh[col];
            float* outp = (nt < C / 16) ? q : s;
            const int cc = (nt < C / 16) ? col : col - C;
            #pragma unroll
            for (int r = 0; r < 4; ++r)
                outp[(size_t)(row0 + g * 4 + r) * C + cc] = acc[r] + bias;
        }
        #pragma unroll
        for (int t2 = 0; t2 < C / 16; ++t2) {
            const int ntK = 2 * C / 16 + t2, ntV = 3 * C / 16 + t2;
            f32x4 aK = {0.f, 0.f, 0.f, 0.f}, aV = {0.f, 0.f, 0.f, 0.f};
            #pragma unroll
            for (int kt = 0; kt < KT; ++kt) {
                aK = __builtin_amdgcn_mfma_f32_16x16x32_f16(afrag[kt], bfrag[kt][ntK], aK, 0, 0, 0);
                aV = __builtin_amdgcn_mfma_f32_16x16x32_f16(afrag[kt], bfrag[kt][ntV], aV, 0, 0, 0);
            }
            const int ck = t2 * 16 + m;
            const float bK = bsh[2 * C + ck], bV = bsh[3 * C + ck];
            #pragma unroll
            for (int r = 0; r < 4; ++r)
                kv[(size_t)(row0 + g * 4 + r) * C + ck] = __floats2half2_rn(aK[r] + bK, aV[r] + bV);
        }
    }
}

// ---------- linear4 via MFMA (layer 2): q | s (fp32) + kv (__half2) ----------
template<int FIN, int C>
__global__ __launch_bounds__(256, 2)
void linear4_mfma_kernel(const float* __restrict__ X,
                         const float* __restrict__ Wq, const float* __restrict__ bq,
                         const float* __restrict__ Wk, const float* __restrict__ bk,
                         const float* __restrict__ Wv, const float* __restrict__ bv,
                         const float* __restrict__ Ws, const float* __restrict__ bs,
                         float* __restrict__ q, __half2* __restrict__ kv,
                         float* __restrict__ s, int n)
{
    constexpr int FOURC = 4 * C;
    constexpr int P  = FIN + 16;
    constexpr int KT = FIN / 32;
    constexpr int NT = FOURC / 16;
    __shared__ _Float16 wsh[FOURC * P] __attribute__((aligned(16)));
    __shared__ float bsh[FOURC];

    for (int i = threadIdx.x; i < FOURC * FIN; i += 256) {
        int col = i / FIN, f = i - (i / FIN) * FIN;
        float w;
        if (col < C)          w = Wq[f * C + col];
        else if (col < 2 * C) w = Ws[f * C + col - C];
        else if (col < 3 * C) w = Wk[f * C + col - 2 * C];
        else                  w = Wv[f * C + col - 3 * C];
        wsh[col * P + f] = (_Float16)w;
    }
    for (int i = threadIdx.x; i < FOURC; i += 256) {
        bsh[i] = (i < C) ? bq[i] : (i < 2 * C) ? bs[i - C]
               : (i < 3 * C) ? bk[i - 2 * C] : bv[i - 3 * C];
    }
    __syncthreads();

    const int lane = threadIdx.x & 63;
    const int wid  = threadIdx.x >> 6;
    const int m = lane & 15, g = lane >> 4;

    half8 bfrag[KT][NT];
    #pragma unroll
    for (int kt = 0; kt < KT; ++kt)
        #pragma unroll
        for (int nt = 0; nt < NT; ++nt)
            bfrag[kt][nt] = *reinterpret_cast<const half8*>(
                &wsh[(nt * 16 + m) * P + kt * 32 + g * 8]);

    const int tiles = n >> 4;
    for (int t = blockIdx.x * 4 + wid; t < tiles; t += gridDim.x * 4) {
        const int row0 = t * 16;
        const float* xr = X + (size_t)(row0 + m) * FIN + g * 8;
        half8 afrag[KT];
        #pragma unroll
        for (int kt = 0; kt < KT; ++kt) {
            float4 u = *reinterpret_cast<const float4*>(xr + kt * 32);
            float4 w = *reinterpret_cast<const float4*>(xr + kt * 32 + 4);
            afrag[kt] = half8{(_Float16)u.x, (_Float16)u.y, (_Float16)u.z, (_Float16)u.w,
                              (_Float16)w.x, (_Float16)w.y, (_Float16)w.z, (_Float16)w.w};
        }
        #pragma unroll
        for (int nt = 0; nt < 2 * C / 16; ++nt) {
            f32x4 acc = {0.f, 0.f, 0.f, 0.f};
            #pragma unroll
            for (int kt = 0; kt < KT; ++kt)
                acc = __builtin_amdgcn_mfma_f32_16x16x32_f16(afrag[kt], bfrag[kt][nt], acc, 0, 0, 0);
            const int col = nt * 16 + m;
            const float bias = bsh[col];
            float* outp = (nt < C / 16) ? q : s;
            const int cc = (nt < C / 16) ? col : col - C;
            #pragma unroll
            for (int r = 0; r < 4; ++r)
                outp[(size_t)(row0 + g * 4 + r) * C + cc] = acc[r] + bias;
        }
        #pragma unroll
        for (int t2 = 0; t2 < C / 16; ++t2) {
            const int ntK = 2 * C / 16 + t2, ntV = 3 * C / 16 + t2;
            f32x4 aK = {0.f, 0.f, 0.f, 0.f}, aV = {0.f, 0.f, 0.f, 0.f};
            #pragma unroll
            for (int kt = 0; kt < KT; ++kt) {
                aK = __builtin_amdgcn_mfma_f32_16x16x32_f16(afrag[kt], bfrag[kt][ntK], aK, 0, 0, 0);
                aV = __builtin_amdgcn_mfma_f32_16x16x32_f16(afrag[kt], bfrag[kt][ntV], aV, 0, 0, 0);
            }
            const int ck = t2 * 16 + m;
            const float bK = bsh[2 * C + ck], bV = bsh[3 * C + ck];
            #pragma unroll
            for (int r = 0; r < 4; ++r)
                kv[(size_t)(row0 + g * 4 + r) * C + ck] = __floats2half2_rn(aK[r] + bK, aV[r] + bV);
        }
    }
}

// ---------- fused conv: 4 ch/lane, factored e-term, masked unroll (R14) ----------
template<int C>
__global__ __launch_bounds__(256)
void conv_fused_kernel(const int* __restrict__ rowptr, const int2* __restrict__ ecsr,
                       const float* __restrict__ q, const __half2* __restrict__ kv,
                       const float* __restrict__ sres,
                       const float* __restrict__ We, const float* __restrict__ be,
                       float* __restrict__ h, float scale, int n)
{
    constexpr int LPE    = C / 4;
    constexpr int EPI    = 64 / LPE;
    constexpr int LOG    = (C == 64) ? 4 : 3;
    constexpr int UNROLL = (C == 64) ? 4 : 2;
    const int wave = threadIdx.x >> 6;
    const int lane = threadIdx.x & 63;
    const int l    = lane & (LPE - 1);
    const int slot = lane >> LOG;
    const int c0   = 4 * l;
    const int node = blockIdx.x * 4 + wave;
    if (node >= n) return;

    const float4 wec = *reinterpret_cast<const float4*>(We + c0);
    const float4 bec = *reinterpret_cast<const float4*>(be + c0);
    const float4 qp  = *reinterpret_cast<const float4*>(q + (size_t)node * C + c0);
    const int r0 = rowptr[node], r1 = rowptr[node + 1];

    float pd1 = fmaf(qp.x, wec.x, fmaf(qp.y, wec.y, fmaf(qp.z, wec.z, qp.w * wec.w)));
    float pd0 = fmaf(qp.x, bec.x, fmaf(qp.y, bec.y, fmaf(qp.z, bec.z, qp.w * bec.w)));
    #pragma unroll
    for (int off = LPE >> 1; off > 0; off >>= 1) {
        pd1 += __shfl_xor(pd1, off);
        pd0 += __shfl_xor(pd0, off);
    }
    const float sd1 = pd1 * scale, sd0 = pd0 * scale;

    float ssum = 0.f, swea = 0.f;
    float a0 = 0.f, a1 = 0.f, a2 = 0.f, a3 = 0.f;
    const int j0 = r0 + slot;
    const int iters = (r1 - j0 + EPI - 1) / EPI;
    for (int it = 0; it < iters; it += UNROLL) {
        int2 epk[UNROLL]; float4 kvr[UNROLL]; bool ok[UNROLL];
        #pragma unroll
        for (int u = 0; u < UNROLL; ++u) {
            int j = j0 + (it + u) * EPI;
            ok[u] = j < r1;
            epk[u] = ecsr[ok[u] ? j : r0];
        }
        #pragma unroll
        for (int u = 0; u < UNROLL; ++u)
            kvr[u] = *reinterpret_cast<const float4*>(kv + (size_t)epk[u].x * C + c0);
        #pragma unroll
        for (int u = 0; u < UNROLL; ++u) {
            float ea = __int_as_float(epk[u].y);
            float2 f0 = __half22float2(*reinterpret_cast<__half2*>(&kvr[u].x));
            float2 f1 = __half22float2(*reinterpret_cast<__half2*>(&kvr[u].y));
            float2 f2 = __half22float2(*reinterpret_cast<__half2*>(&kvr[u].z));
            float2 f3 = __half22float2(*reinterpret_cast<__half2*>(&kvr[u].w));
            float p = fmaf(qp.x, f0.x, fmaf(qp.y, f1.x, fmaf(qp.z, f2.x, qp.w * f3.x)));
            #pragma unroll
            for (int off = LPE >> 1; off > 0; off >>= 1) p += __shfl_xor(p, off);
            float w = __expf(fmaf(scale, p, fmaf(sd1, ea, sd0)));
            w = ok[u] ? w : 0.f;
            ssum += w;
            swea = fmaf(w, ea, swea);
            a0 = fmaf(w, f0.y, a0);
            a1 = fmaf(w, f1.y, a1);
            a2 = fmaf(w, f2.y, a2);
            a3 = fmaf(w, f3.y, a3);
        }
    }

    #pragma unroll
    for (int off = LPE; off < 64; off <<= 1) {
        ssum += __shfl_xor(ssum, off);
        swea += __shfl_xor(swea, off);
        a0   += __shfl_xor(a0, off);
        a1   += __shfl_xor(a1, off);
        a2   += __shfl_xor(a2, off);
        a3   += __shfl_xor(a3, off);
    }

    if (slot == 0) {
        float inv = 1.f / (ssum + 1e-16f);
        float t0 = fmaf(wec.x, swea, fmaf(bec.x, ssum, a0));
        float t1 = fmaf(wec.y, swea, fmaf(bec.y, ssum, a1));
        float t2 = fmaf(wec.z, swea, fmaf(bec.z, ssum, a2));
        float t3 = fmaf(wec.w, swea, fmaf(bec.w, ssum, a3));
        float4 sr = *reinterpret_cast<const float4*>(sres + (size_t)node * C + c0);
        float h0 = fmaf(t0, inv, sr.x);
        float h1 = fmaf(t1, inv, sr.y);
        float h2v = fmaf(t2, inv, sr.z);
        float h3 = fmaf(t3, inv, sr.w);
        h0 = (h0 > 0.f) ? h0 : expm1f(h0);
        h1 = (h1 > 0.f) ? h1 : expm1f(h1);
        h2v = (h2v > 0.f) ? h2v : expm1f(h2v);
        h3 = (h3 > 0.f) ? h3 : expm1f(h3);
        *reinterpret_cast<float4*>(h + (size_t)node * C + c0) = make_float4(h0, h1, h2v, h3);
    }
}

// ---------- fused fc1(MFMA+ELU) + fc2 + log_softmax ----------
template<int FIN, int COUT, int NCLS>
__global__ __launch_bounds__(256, 2)
void linear_head_mfma_kernel(const float* __restrict__ X,
                             const float* __restrict__ W1, const float* __restrict__ b1,
                             const float* __restrict__ W2, const float* __restrict__ b2,
                             float* __restrict__ out, int n)
{
    constexpr int P  = FIN + 16;
    constexpr int KT = FIN / 32;
    constexpr int NT = COUT / 16;
    __shared__ _Float16 wsh[COUT * P] __attribute__((aligned(16)));
    __shared__ float bsh[COUT];
    __shared__ float w2sh[COUT * NCLS];
    __shared__ float b2sh[NCLS];
    for (int i = threadIdx.x; i < COUT * FIN; i += 256) {
        int col = i / FIN, f = i - (i / FIN) * FIN;
        wsh[col * P + f] = (_Float16)W1[f * COUT + col];
    }
    for (int i = threadIdx.x; i < COUT; i += 256) bsh[i] = b1[i];
    for (int i = threadIdx.x; i < COUT * NCLS; i += 256) w2sh[i] = W2[i];
    for (int i = threadIdx.x; i < NCLS; i += 256) b2sh[i] = b2[i];
    __syncthreads();

    const int lane = threadIdx.x & 63;
    const int wid  = threadIdx.x >> 6;
    const int m = lane & 15, g = lane >> 4;

    half8 bfrag[KT][NT];
    #pragma unroll
    for (int kt = 0; kt < KT; ++kt)
        #pragma unroll
        for (int nt = 0; nt < NT; ++nt)
            bfrag[kt][nt] = *reinterpret_cast<const half8*>(
                &wsh[(nt * 16 + m) * P + kt * 32 + g * 8]);

    const int tiles = n >> 4;
    for (int t = blockIdx.x * 4 + wid; t < tiles; t += gridDim.x * 4) {
        const int row0 = t * 16;
        const float* xr = X + (size_t)(row0 + m) * FIN + g * 8;
        half8 afrag[KT];
        #pragma unroll
        for (int kt = 0; kt < KT; ++kt) {
            float4 u = *reinterpret_cast<const float4*>(xr + kt * 32);
            float4 w = *reinterpret_cast<const float4*>(xr + kt * 32 + 4);
            afrag[kt] = half8{(_Float16)u.x, (_Float16)u.y, (_Float16)u.z, (_Float16)u.w,
                              (_Float16)w.x, (_Float16)w.y, (_Float16)w.z, (_Float16)w.w};
        }
        // fc1: hv[nt][r] = elu(mfma + bias) held in registers
        float hv[NT][4];
        #pragma unroll
        for (int nt = 0; nt < NT; ++nt) {
            f32x4 acc = {0.f, 0.f, 0.f, 0.f};
            #pragma unroll
            for (int kt = 0; kt < KT; ++kt)
                acc = __builtin_amdgcn_mfma_f32_16x16x32_f16(afrag[kt], bfrag[kt][nt], acc, 0, 0, 0);
            const float bias = bsh[nt * 16 + m];
            #pragma unroll
            for (int r = 0; r < 4; ++r) {
                float v = acc[r] + bias;
                hv[nt][r] = (v > 0.f) ? v : expm1f(v);
            }
        }
        // fc2 partials: this lane holds cols {nt*16+m}; accumulate over its 8 cols
        float part[4][NCLS];
        #pragma unroll
        for (int r = 0; r < 4; ++r)
            #pragma unroll
            for (int c = 0; c < NCLS; ++c) part[r][c] = 0.f;
        #pragma unroll
        for (int nt = 0; nt < NT; ++nt) {
            float w2r[NCLS];
            #pragma unroll
            for (int c = 0; c < NCLS; ++c) w2r[c] = w2sh[(nt * 16 + m) * NCLS + c];
            #pragma unroll
            for (int r = 0; r < 4; ++r)
                #pragma unroll
                for (int c = 0; c < NCLS; ++c)
                    part[r][c] = fmaf(hv[nt][r], w2r[c], part[r][c]);
        }
        // reduce over the 16 col-lanes (m dimension)
        #pragma unroll
        for (int off = 1; off < 16; off <<= 1)
            #pragma unroll
            for (int r = 0; r < 4; ++r)
                #pragma unroll
                for (int c = 0; c < NCLS; ++c)
                    part[r][c] += __shfl_xor(part[r][c], off);
        // lanes m<4 finish row r=m: bias, log_softmax, write
        if (m < 4) {
            const int r = m;
            const int row = row0 + g * 4 + r;
            float logit[NCLS];
            #pragma unroll
            for (int c = 0; c < NCLS; ++c) logit[c] = part[r][c] + b2sh[c];
            float mx = logit[0];
            #pragma unroll
            for (int c = 1; c < NCLS; ++c) mx = fmaxf(mx, logit[c]);
            float sum = 0.f;
            #pragma unroll
            for (int c = 0; c < NCLS; ++c) sum += __expf(logit[c] - mx);
            float lse = mx + logf(sum);
            #pragma unroll
            for (int c = 0; c < NCLS; ++c)
                out[(size_t)row * NCLS + c] = logit[c] - lse;
        }
    }
}

extern "C" void kernel_launch(void* const* d_in, const int* in_sizes, int n_in,
                              void* d_out, int out_size, void* d_ws, size_t ws_size,
                              hipStream_t stream) {
    const float* x   = (const float*)d_in[0];
    const int*   ei  = (const int*)d_in[1];
    const float* ea  = (const float*)d_in[2];
    const float *Wq1 = (const float*)d_in[3],  *bq1 = (const float*)d_in[4];
    const float *Wk1 = (const float*)d_in[5],  *bk1 = (const float*)d_in[6];
    const float *Wv1 = (const float*)d_in[7],  *bv1 = (const float*)d_in[8];
    const float *We1 = (const float*)d_in[9],  *be1 = (const float*)d_in[10];
    const float *Ws1 = (const float*)d_in[11], *bs1 = (const float*)d_in[12];
    const float *Wq2 = (const float*)d_in[13], *bq2 = (const float*)d_in[14];
    const float *Wk2 = (const float*)d_in[15], *bk2 = (const float*)d_in[16];
    const float *Wv2 = (const float*)d_in[17], *bv2 = (const float*)d_in[18];
    const float *We2 = (const float*)d_in[19], *be2 = (const float*)d_in[20];
    const float *Ws2 = (const float*)d_in[21], *bs2 = (const float*)d_in[22];
    const float *Wf1 = (const float*)d_in[23], *bf1 = (const float*)d_in[24];
    const float *Wf2 = (const float*)d_in[25], *bf2 = (const float*)d_in[26];

    const int N = in_sizes[0] / 64;   // 100000
    const int E = in_sizes[2];        // 1600000
    const int* src = ei;              // edge_index[0]
    const int* dst = ei + E;          // edge_index[1]

    float* wsf = (float*)d_ws;
    const size_t N64 = (size_t)N * 64;
    float* q      = wsf;                      // N*64
    __half2* kv   = (__half2*)(q + N64);      // N*64 half2 (k,v packed)
    float* s      = (float*)(kv + N64);       // N*64 (skip proj)
    float* h1     = s + N64;                  // N*32
    float* h2     = h1 + (size_t)N * 32;      // N*64
    int* deg      = (int*)(h2 + N64);         // N
    int* rowptr   = deg + N;                  // N+1
    int* bsum     = rowptr + N + 1;           // SCAN_NB
    int* boff     = bsum + SCAN_NB;           // SCAN_NB
    int* rank     = boff + SCAN_NB;           // E
    int2* ecsr    = (int2*)(rank + E);        // E (packed {src, eattr})

    float* out = (float*)d_out;

    // ---- CSR build overlapped with linear4-L1 ----
    hipMemsetAsync(deg, 0, (size_t)N * 4, stream);
    count_linear4_kernel<64, 32><<<CNT_NB / 2 * 3, 256, 0, stream>>>(
        dst, deg, rank, E,
        x, Wq1, bq1, Wk1, bk1, Wv1, bv1, Ws1, bs1, q, kv, s, N);
    blocksum_kernel<<<SCAN_NB, 256, 0, stream>>>(deg, bsum, N);
    scanb_kernel<<<1, 256, 0, stream>>>(bsum, boff, rowptr + N, SCAN_NB);
    writeptr_kernel<<<SCAN_NB, 256, 0, stream>>>(deg, boff, rowptr, N);
    fill_pack_kernel<<<4096, 256, 0, stream>>>(src, dst, ea, rowptr, rank, ecsr, E);

    const int convGrid = (N + 3) / 4;

    // ---- layer 1 conv (C=32) ----
    conv_fused_kernel<32><<<convGrid, 256, 0, stream>>>(
        rowptr, ecsr, q, kv, s, We1, be1, h1, 0.17677669529663687f, N);

    // ---- layer 2 (C=64) ----
    linear4_mfma_kernel<32, 64><<<1024, 256, 0, stream>>>(
        h1, Wq2, bq2, Wk2, bk2, Wv2, bv2, Ws2, bs2, q, kv, s, N);
    conv_fused_kernel<64><<<convGrid, 256, 0, stream>>>(
        rowptr, ecsr, q, kv, s, We2, be2, h2, 0.125f, N);

    // ---- fused MLP head: fc1 + ELU + fc2 + log_softmax ----
    linear_head_mfma_kernel<64, 128, 10><<<1024, 256, 0, stream>>>(
        h2, Wf1, bf1, Wf2, bf2, out, N);
}

// Round 18
// 301.724 us; speedup vs baseline: 1.2320x; 1.0641x over previous
//
#include <hip/hip_runtime.h>
#include <hip/hip_fp16.h>
#include <math.h>

// TransformerConvNet: 2x TransformerConv(heads=1) + ELU + MLP head + log_softmax
// N=100000 nodes, E=1600000 edges, F_IN=64, C1=32, C2=64, H1=128, NC=10
//
// R17 (resubmit after infra failure): fused head rebuilt — fc2 on MFMA via
// wave-private LDS transpose of the fc1 tile (kills R15's 320-fma/160-shfl
// scalar fc2 + register spill). Everything else unchanged from R15.

#define SCAN_NB 256

typedef _Float16 half8 __attribute__((ext_vector_type(8)));
typedef float f32x4 __attribute__((ext_vector_type(4)));

// ---------- CSR build ----------
__global__ __launch_bounds__(256)
void blocksum_kernel(const int* __restrict__ deg, int* __restrict__ bsum, int n) {
    __shared__ int ls[256];
    const int chunk = (n + gridDim.x - 1) / gridDim.x;
    const int b0 = blockIdx.x * chunk;
    const int b1 = (b0 + chunk < n) ? b0 + chunk : n;
    int s = 0;
    for (int i = b0 + threadIdx.x; i < b1; i += 256) s += deg[i];
    ls[threadIdx.x] = s;
    __syncthreads();
    for (int off = 128; off > 0; off >>= 1) {
        if (threadIdx.x < off) ls[threadIdx.x] += ls[threadIdx.x + off];
        __syncthreads();
    }
    if (threadIdx.x == 0) bsum[blockIdx.x] = ls[0];
}

__global__ __launch_bounds__(256)
void scanb_kernel(const int* __restrict__ bsum, int* __restrict__ boff,
                  int* __restrict__ total, int nb) {
    __shared__ int ls[256];
    const int t = threadIdx.x;
    int v = (t < nb) ? bsum[t] : 0;
    ls[t] = v;
    __syncthreads();
    for (int off = 1; off < 256; off <<= 1) {
        int u = (t >= off) ? ls[t - off] : 0;
        __syncthreads();
        ls[t] += u;
        __syncthreads();
    }
    if (t < nb) boff[t] = ls[t] - v;
    if (t == 255) *total = ls[255];
}

__global__ __launch_bounds__(256)
void writeptr_kernel(const int* __restrict__ deg, const int* __restrict__ boff,
                     int* __restrict__ rowptr, int n) {
    __shared__ int ls[256];
    const int chunk = (n + gridDim.x - 1) / gridDim.x;
    const int b0 = blockIdx.x * chunk;
    const int b1 = (b0 + chunk < n) ? b0 + chunk : n;
    const int tchunk = (chunk + 255) / 256;
    const int t0 = b0 + threadIdx.x * tchunk;
    const int t1 = (t0 + tchunk < b1) ? t0 + tchunk : b1;
    int s = 0;
    for (int i = t0; i < t1; ++i) s += deg[i];
    ls[threadIdx.x] = s;
    __syncthreads();
    for (int off = 1; off < 256; off <<= 1) {
        int u = (threadIdx.x >= off) ? ls[threadIdx.x - off] : 0;
        __syncthreads();
        ls[threadIdx.x] += u;
        __syncthreads();
    }
    int run = boff[blockIdx.x] + ls[threadIdx.x] - s;
    for (int i = t0; i < t1; ++i) { rowptr[i] = run; run += deg[i]; }
}

__global__ __launch_bounds__(256)
void fill_pack_kernel(const int* __restrict__ src, const int* __restrict__ dst,
                      const float* __restrict__ eattr,
                      const int* __restrict__ rowptr, const int* __restrict__ rank,
                      int2* __restrict__ ecsr, int e) {
    for (int i = blockIdx.x * 256 + threadIdx.x; i < e; i += gridDim.x * 256) {
        int p = rowptr[dst[i]] + rank[i];
        ecsr[p] = make_int2(src[i], __float_as_int(eattr[i]));
    }
}

// ---------- fused: count_rank (blocks role<2) + linear4-L1 MFMA (role==2) ----------
#define CNT_NB 2048
#define L4_NB  1024
template<int FIN, int C>
__global__ __launch_bounds__(256, 2)
void count_linear4_kernel(const int* __restrict__ dst, int* __restrict__ deg,
                          int* __restrict__ rank, int e,
                          const float* __restrict__ X,
                          const float* __restrict__ Wq, const float* __restrict__ bq,
                          const float* __restrict__ Wk, const float* __restrict__ bk,
                          const float* __restrict__ Wv, const float* __restrict__ bv,
                          const float* __restrict__ Ws, const float* __restrict__ bs,
                          float* __restrict__ q, __half2* __restrict__ kv,
                          float* __restrict__ s, int n)
{
    constexpr int FOURC = 4 * C;
    constexpr int P  = FIN + 16;
    constexpr int KT = FIN / 32;
    constexpr int NT = FOURC / 16;
    __shared__ _Float16 wsh[FOURC * P] __attribute__((aligned(16)));
    __shared__ float bsh[FOURC];

    const int b3 = blockIdx.x / 3, role = blockIdx.x % 3;
    if (role < 2) {
        const int cb = b3 * 2 + role;
        for (int i = cb * 256 + threadIdx.x; i < e; i += CNT_NB * 256)
            rank[i] = atomicAdd(deg + dst[i], 1);
        return;
    }

    const int lb = b3;
    for (int i = threadIdx.x; i < FOURC * FIN; i += 256) {
        int col = i / FIN, f = i - (i / FIN) * FIN;
        float w;
        if (col < C)          w = Wq[f * C + col];
        else if (col < 2 * C) w = Ws[f * C + col - C];
        else if (col < 3 * C) w = Wk[f * C + col - 2 * C];
        else                  w = Wv[f * C + col - 3 * C];
        wsh[col * P + f] = (_Float16)w;
    }
    for (int i = threadIdx.x; i < FOURC; i += 256) {
        bsh[i] = (i < C) ? bq[i] : (i < 2 * C) ? bs[i - C]
               : (i < 3 * C) ? bk[i - 2 * C] : bv[i - 3 * C];
    }
    __syncthreads();

    const int lane = threadIdx.x & 63;
    const int wid  = threadIdx.x >> 6;
    const int m = lane & 15, g = lane >> 4;

    half8 bfrag[KT][NT];
    #pragma unroll
    for (int kt = 0; kt < KT; ++kt)
        #pragma unroll
        for (int nt = 0; nt < NT; ++nt)
            bfrag[kt][nt] = *reinterpret_cast<const half8*>(
                &wsh[(nt * 16 + m) * P + kt * 32 + g * 8]);

    const int tiles = n >> 4;
    for (int t = lb * 4 + wid; t < tiles; t += L4_NB * 4) {
        const int row0 = t * 16;
        const float* xr = X + (size_t)(row0 + m) * FIN + g * 8;
        half8 afrag[KT];
        #pragma unroll
        for (int kt = 0; kt < KT; ++kt) {
            float4 u = *reinterpret_cast<const float4*>(xr + kt * 32);
            float4 w = *reinterpret_cast<const float4*>(xr + kt * 32 + 4);
            afrag[kt] = half8{(_Float16)u.x, (_Float16)u.y, (_Float16)u.z, (_Float16)u.w,
                              (_Float16)w.x, (_Float16)w.y, (_Float16)w.z, (_Float16)w.w};
        }
        #pragma unroll
        for (int nt = 0; nt < 2 * C / 16; ++nt) {
            f32x4 acc = {0.f, 0.f, 0.f, 0.f};
            #pragma unroll
            for (int kt = 0; kt < KT; ++kt)
                acc = __builtin_amdgcn_mfma_f32_16x16x32_f16(afrag[kt], bfrag[kt][nt], acc, 0, 0, 0);
            const int col = nt * 16 + m;
            const float bias = bsh[col];
            float* outp = (nt < C / 16) ? q : s;
            const int cc = (nt < C / 16) ? col : col - C;
            #pragma unroll
            for (int r = 0; r < 4; ++r)
                outp[(size_t)(row0 + g * 4 + r) * C + cc] = acc[r] + bias;
        }
        #pragma unroll
        for (int t2 = 0; t2 < C / 16; ++t2) {
            const int ntK = 2 * C / 16 + t2, ntV = 3 * C / 16 + t2;
            f32x4 aK = {0.f, 0.f, 0.f, 0.f}, aV = {0.f, 0.f, 0.f, 0.f};
            #pragma unroll
            for (int kt = 0; kt < KT; ++kt) {
                aK = __builtin_amdgcn_mfma_f32_16x16x32_f16(afrag[kt], bfrag[kt][ntK], aK, 0, 0, 0);
                aV = __builtin_amdgcn_mfma_f32_16x16x32_f16(afrag[kt], bfrag[kt][ntV], aV, 0, 0, 0);
            }
            const int ck = t2 * 16 + m;
            const float bK = bsh[2 * C + ck], bV = bsh[3 * C + ck];
            #pragma unroll
            for (int r = 0; r < 4; ++r)
                kv[(size_t)(row0 + g * 4 + r) * C + ck] = __floats2half2_rn(aK[r] + bK, aV[r] + bV);
        }
    }
}

// ---------- linear4 via MFMA (layer 2): q | s (fp32) + kv (__half2) ----------
template<int FIN, int C>
__global__ __launch_bounds__(256, 2)
void linear4_mfma_kernel(const float* __restrict__ X,
                         const float* __restrict__ Wq, const float* __restrict__ bq,
                         const float* __restrict__ Wk, const float* __restrict__ bk,
                         const float* __restrict__ Wv, const float* __restrict__ bv,
                         const float* __restrict__ Ws, const float* __restrict__ bs,
                         float* __restrict__ q, __half2* __restrict__ kv,
                         float* __restrict__ s, int n)
{
    constexpr int FOURC = 4 * C;
    constexpr int P  = FIN + 16;
    constexpr int KT = FIN / 32;
    constexpr int NT = FOURC / 16;
    __shared__ _Float16 wsh[FOURC * P] __attribute__((aligned(16)));
    __shared__ float bsh[FOURC];

    for (int i = threadIdx.x; i < FOURC * FIN; i += 256) {
        int col = i / FIN, f = i - (i / FIN) * FIN;
        float w;
        if (col < C)          w = Wq[f * C + col];
        else if (col < 2 * C) w = Ws[f * C + col - C];
        else if (col < 3 * C) w = Wk[f * C + col - 2 * C];
        else                  w = Wv[f * C + col - 3 * C];
        wsh[col * P + f] = (_Float16)w;
    }
    for (int i = threadIdx.x; i < FOURC; i += 256) {
        bsh[i] = (i < C) ? bq[i] : (i < 2 * C) ? bs[i - C]
               : (i < 3 * C) ? bk[i - 2 * C] : bv[i - 3 * C];
    }
    __syncthreads();

    const int lane = threadIdx.x & 63;
    const int wid  = threadIdx.x >> 6;
    const int m = lane & 15, g = lane >> 4;

    half8 bfrag[KT][NT];
    #pragma unroll
    for (int kt = 0; kt < KT; ++kt)
        #pragma unroll
        for (int nt = 0; nt < NT; ++nt)
            bfrag[kt][nt] = *reinterpret_cast<const half8*>(
                &wsh[(nt * 16 + m) * P + kt * 32 + g * 8]);

    const int tiles = n >> 4;
    for (int t = blockIdx.x * 4 + wid; t < tiles; t += gridDim.x * 4) {
        const int row0 = t * 16;
        const float* xr = X + (size_t)(row0 + m) * FIN + g * 8;
        half8 afrag[KT];
        #pragma unroll
        for (int kt = 0; kt < KT; ++kt) {
            float4 u = *reinterpret_cast<const float4*>(xr + kt * 32);
            float4 w = *reinterpret_cast<const float4*>(xr + kt * 32 + 4);
            afrag[kt] = half8{(_Float16)u.x, (_Float16)u.y, (_Float16)u.z, (_Float16)u.w,
                              (_Float16)w.x, (_Float16)w.y, (_Float16)w.z, (_Float16)w.w};
        }
        #pragma unroll
        for (int nt = 0; nt < 2 * C / 16; ++nt) {
            f32x4 acc = {0.f, 0.f, 0.f, 0.f};
            #pragma unroll
            for (int kt = 0; kt < KT; ++kt)
                acc = __builtin_amdgcn_mfma_f32_16x16x32_f16(afrag[kt], bfrag[kt][nt], acc, 0, 0, 0);
            const int col = nt * 16 + m;
            const float bias = bsh[col];
            float* outp = (nt < C / 16) ? q : s;
            const int cc = (nt < C / 16) ? col : col - C;
            #pragma unroll
            for (int r = 0; r < 4; ++r)
                outp[(size_t)(row0 + g * 4 + r) * C + cc] = acc[r] + bias;
        }
        #pragma unroll
        for (int t2 = 0; t2 < C / 16; ++t2) {
            const int ntK = 2 * C / 16 + t2, ntV = 3 * C / 16 + t2;
            f32x4 aK = {0.f, 0.f, 0.f, 0.f}, aV = {0.f, 0.f, 0.f, 0.f};
            #pragma unroll
            for (int kt = 0; kt < KT; ++kt) {
                aK = __builtin_amdgcn_mfma_f32_16x16x32_f16(afrag[kt], bfrag[kt][ntK], aK, 0, 0, 0);
                aV = __builtin_amdgcn_mfma_f32_16x16x32_f16(afrag[kt], bfrag[kt][ntV], aV, 0, 0, 0);
            }
            const int ck = t2 * 16 + m;
            const float bK = bsh[2 * C + ck], bV = bsh[3 * C + ck];
            #pragma unroll
            for (int r = 0; r < 4; ++r)
                kv[(size_t)(row0 + g * 4 + r) * C + ck] = __floats2half2_rn(aK[r] + bK, aV[r] + bV);
        }
    }
}

// ---------- fused conv: 4 ch/lane, factored e-term, masked unroll (R14) ----------
template<int C>
__global__ __launch_bounds__(256)
void conv_fused_kernel(const int* __restrict__ rowptr, const int2* __restrict__ ecsr,
                       const float* __restrict__ q, const __half2* __restrict__ kv,
                       const float* __restrict__ sres,
                       const float* __restrict__ We, const float* __restrict__ be,
                       float* __restrict__ h, float scale, int n)
{
    constexpr int LPE    = C / 4;
    constexpr int EPI    = 64 / LPE;
    constexpr int LOG    = (C == 64) ? 4 : 3;
    constexpr int UNROLL = (C == 64) ? 4 : 2;
    const int wave = threadIdx.x >> 6;
    const int lane = threadIdx.x & 63;
    const int l    = lane & (LPE - 1);
    const int slot = lane >> LOG;
    const int c0   = 4 * l;
    const int node = blockIdx.x * 4 + wave;
    if (node >= n) return;

    const float4 wec = *reinterpret_cast<const float4*>(We + c0);
    const float4 bec = *reinterpret_cast<const float4*>(be + c0);
    const float4 qp  = *reinterpret_cast<const float4*>(q + (size_t)node * C + c0);
    const int r0 = rowptr[node], r1 = rowptr[node + 1];

    float pd1 = fmaf(qp.x, wec.x, fmaf(qp.y, wec.y, fmaf(qp.z, wec.z, qp.w * wec.w)));
    float pd0 = fmaf(qp.x, bec.x, fmaf(qp.y, bec.y, fmaf(qp.z, bec.z, qp.w * bec.w)));
    #pragma unroll
    for (int off = LPE >> 1; off > 0; off >>= 1) {
        pd1 += __shfl_xor(pd1, off);
        pd0 += __shfl_xor(pd0, off);
    }
    const float sd1 = pd1 * scale, sd0 = pd0 * scale;

    float ssum = 0.f, swea = 0.f;
    float a0 = 0.f, a1 = 0.f, a2 = 0.f, a3 = 0.f;
    const int j0 = r0 + slot;
    const int iters = (r1 - j0 + EPI - 1) / EPI;
    for (int it = 0; it < iters; it += UNROLL) {
        int2 epk[UNROLL]; float4 kvr[UNROLL]; bool ok[UNROLL];
        #pragma unroll
        for (int u = 0; u < UNROLL; ++u) {
            int j = j0 + (it + u) * EPI;
            ok[u] = j < r1;
            epk[u] = ecsr[ok[u] ? j : r0];
        }
        #pragma unroll
        for (int u = 0; u < UNROLL; ++u)
            kvr[u] = *reinterpret_cast<const float4*>(kv + (size_t)epk[u].x * C + c0);
        #pragma unroll
        for (int u = 0; u < UNROLL; ++u) {
            float ea = __int_as_float(epk[u].y);
            float2 f0 = __half22float2(*reinterpret_cast<__half2*>(&kvr[u].x));
            float2 f1 = __half22float2(*reinterpret_cast<__half2*>(&kvr[u].y));
            float2 f2 = __half22float2(*reinterpret_cast<__half2*>(&kvr[u].z));
            float2 f3 = __half22float2(*reinterpret_cast<__half2*>(&kvr[u].w));
            float p = fmaf(qp.x, f0.x, fmaf(qp.y, f1.x, fmaf(qp.z, f2.x, qp.w * f3.x)));
            #pragma unroll
            for (int off = LPE >> 1; off > 0; off >>= 1) p += __shfl_xor(p, off);
            float w = __expf(fmaf(scale, p, fmaf(sd1, ea, sd0)));
            w = ok[u] ? w : 0.f;
            ssum += w;
            swea = fmaf(w, ea, swea);
            a0 = fmaf(w, f0.y, a0);
            a1 = fmaf(w, f1.y, a1);
            a2 = fmaf(w, f2.y, a2);
            a3 = fmaf(w, f3.y, a3);
        }
    }

    #pragma unroll
    for (int off = LPE; off < 64; off <<= 1) {
        ssum += __shfl_xor(ssum, off);
        swea += __shfl_xor(swea, off);
        a0   += __shfl_xor(a0, off);
        a1   += __shfl_xor(a1, off);
        a2   += __shfl_xor(a2, off);
        a3   += __shfl_xor(a3, off);
    }

    if (slot == 0) {
        float inv = 1.f / (ssum + 1e-16f);
        float t0 = fmaf(wec.x, swea, fmaf(bec.x, ssum, a0));
        float t1 = fmaf(wec.y, swea, fmaf(bec.y, ssum, a1));
        float t2 = fmaf(wec.z, swea, fmaf(bec.z, ssum, a2));
        float t3 = fmaf(wec.w, swea, fmaf(bec.w, ssum, a3));
        float4 sr = *reinterpret_cast<const float4*>(sres + (size_t)node * C + c0);
        float h0 = fmaf(t0, inv, sr.x);
        float h1 = fmaf(t1, inv, sr.y);
        float h2v = fmaf(t2, inv, sr.z);
        float h3 = fmaf(t3, inv, sr.w);
        h0 = (h0 > 0.f) ? h0 : expm1f(h0);
        h1 = (h1 > 0.f) ? h1 : expm1f(h1);
        h2v = (h2v > 0.f) ? h2v : expm1f(h2v);
        h3 = (h3 > 0.f) ? h3 : expm1f(h3);
        *reinterpret_cast<float4*>(h + (size_t)node * C + c0) = make_float4(h0, h1, h2v, h3);
    }
}

// ---------- fused head: fc1 MFMA + ELU -> LDS transpose -> fc2 MFMA + log_softmax ----------
template<int FIN, int COUT, int NCLS>
__global__ __launch_bounds__(256, 2)
void linear_head_mfma_kernel(const float* __restrict__ X,
                             const float* __restrict__ W1, const float* __restrict__ b1,
                             const float* __restrict__ W2, const float* __restrict__ b2,
                             float* __restrict__ out, int n)
{
    constexpr int P   = FIN + 16;    // 80
    constexpr int KT  = FIN / 32;    // 2
    constexpr int NT  = COUT / 16;   // 8
    constexpr int KT2 = COUT / 32;   // 4
    constexpr int HP  = COUT + 8;    // 136 (halfs): b128 A-reads land 2-way (free)
    __shared__ _Float16 wsh[COUT * P] __attribute__((aligned(16)));   // 20.5 KB
    __shared__ float bsh[COUT];
    __shared__ _Float16 hsh[4][16 * HP] __attribute__((aligned(16))); // 17.4 KB (wave-private)
    __shared__ float b2sh[NCLS];

    for (int i = threadIdx.x; i < COUT * FIN; i += 256) {
        int col = i / FIN, f = i - (i / FIN) * FIN;
        wsh[col * P + f] = (_Float16)W1[f * COUT + col];
    }
    for (int i = threadIdx.x; i < COUT; i += 256) bsh[i] = b1[i];
    for (int i = threadIdx.x; i < NCLS; i += 256) b2sh[i] = b2[i];
    __syncthreads();

    const int lane = threadIdx.x & 63;
    const int wid  = threadIdx.x >> 6;
    const int m = lane & 15, g = lane >> 4;

    // W1 B-frags (fc1)
    half8 bfrag[KT][NT];
    #pragma unroll
    for (int kt = 0; kt < KT; ++kt)
        #pragma unroll
        for (int nt = 0; nt < NT; ++nt)
            bfrag[kt][nt] = *reinterpret_cast<const half8*>(
                &wsh[(nt * 16 + m) * P + kt * 32 + g * 8]);

    // W2 B-frags (fc2, cols padded to 16): lane (m,g) holds W2[k= kt*32+g*8+j][m]
    half8 bfrag2[KT2];
    #pragma unroll
    for (int kt = 0; kt < KT2; ++kt) {
        half8 tt;
        #pragma unroll
        for (int j = 0; j < 8; ++j) {
            float w = (m < NCLS) ? W2[(kt * 32 + g * 8 + j) * NCLS + m] : 0.f;
            tt[j] = (_Float16)w;
        }
        bfrag2[kt] = tt;
    }

    _Float16* hrow = &hsh[wid][0];
    const int tiles = n >> 4;
    for (int t = blockIdx.x * 4 + wid; t < tiles; t += gridDim.x * 4) {
        const int row0 = t * 16;
        const float* xr = X + (size_t)(row0 + m) * FIN + g * 8;
        half8 afrag[KT];
        #pragma unroll
        for (int kt = 0; kt < KT; ++kt) {
            float4 u = *reinterpret_cast<const float4*>(xr + kt * 32);
            float4 w = *reinterpret_cast<const float4*>(xr + kt * 32 + 4);
            afrag[kt] = half8{(_Float16)u.x, (_Float16)u.y, (_Float16)u.z, (_Float16)u.w,
                              (_Float16)w.x, (_Float16)w.y, (_Float16)w.z, (_Float16)w.w};
        }
        // fc1 per nt: MFMA + bias + ELU -> fp16 -> LDS (C/D layout transpose)
        #pragma unroll
        for (int nt = 0; nt < NT; ++nt) {
            f32x4 acc = {0.f, 0.f, 0.f, 0.f};
            #pragma unroll
            for (int kt = 0; kt < KT; ++kt)
                acc = __builtin_amdgcn_mfma_f32_16x16x32_f16(afrag[kt], bfrag[kt][nt], acc, 0, 0, 0);
            const float bias = bsh[nt * 16 + m];
            #pragma unroll
            for (int r = 0; r < 4; ++r) {
                float v = acc[r] + bias;
                v = (v > 0.f) ? v : expm1f(v);
                hrow[(g * 4 + r) * HP + nt * 16 + m] = (_Float16)v;
            }
        }
        // fc2: A-frags from LDS (same-wave dependency; compiler inserts lgkmcnt)
        f32x4 acc2 = {0.f, 0.f, 0.f, 0.f};
        #pragma unroll
        for (int kt = 0; kt < KT2; ++kt) {
            half8 a2 = *reinterpret_cast<const half8*>(&hrow[m * HP + kt * 32 + g * 8]);
            acc2 = __builtin_amdgcn_mfma_f32_16x16x32_f16(a2, bfrag2[kt], acc2, 0, 0, 0);
        }
        // logits: class = m, row = row0 + g*4 + r ; softmax across m-lanes (masked >= NCLS)
        #pragma unroll
        for (int r = 0; r < 4; ++r) {
            float logit = acc2[r] + ((m < NCLS) ? b2sh[m] : -1e30f);
            float mx = logit;
            #pragma unroll
            for (int off = 1; off < 16; off <<= 1) mx = fmaxf(mx, __shfl_xor(mx, off));
            float ex = (m < NCLS) ? __expf(logit - mx) : 0.f;
            float sum = ex;
            #pragma unroll
            for (int off = 1; off < 16; off <<= 1) sum += __shfl_xor(sum, off);
            float lse = mx + logf(sum);
            if (m < NCLS)
                out[(size_t)(row0 + g * 4 + r) * NCLS + m] = logit - lse;
        }
    }
}

extern "C" void kernel_launch(void* const* d_in, const int* in_sizes, int n_in,
                              void* d_out, int out_size, void* d_ws, size_t ws_size,
                              hipStream_t stream) {
    const float* x   = (const float*)d_in[0];
    const int*   ei  = (const int*)d_in[1];
    const float* ea  = (const float*)d_in[2];
    const float *Wq1 = (const float*)d_in[3],  *bq1 = (const float*)d_in[4];
    const float *Wk1 = (const float*)d_in[5],  *bk1 = (const float*)d_in[6];
    const float *Wv1 = (const float*)d_in[7],  *bv1 = (const float*)d_in[8];
    const float *We1 = (const float*)d_in[9],  *be1 = (const float*)d_in[10];
    const float *Ws1 = (const float*)d_in[11], *bs1 = (const float*)d_in[12];
    const float *Wq2 = (const float*)d_in[13], *bq2 = (const float*)d_in[14];
    const float *Wk2 = (const float*)d_in[15], *bk2 = (const float*)d_in[16];
    const float *Wv2 = (const float*)d_in[17], *bv2 = (const float*)d_in[18];
    const float *We2 = (const float*)d_in[19], *be2 = (const float*)d_in[20];
    const float *Ws2 = (const float*)d_in[21], *bs2 = (const float*)d_in[22];
    const float *Wf1 = (const float*)d_in[23], *bf1 = (const float*)d_in[24];
    const float *Wf2 = (const float*)d_in[25], *bf2 = (const float*)d_in[26];

    const int N = in_sizes[0] / 64;   // 100000
    const int E = in_sizes[2];        // 1600000
    const int* src = ei;              // edge_index[0]
    const int* dst = ei + E;          // edge_index[1]

    float* wsf = (float*)d_ws;
    const size_t N64 = (size_t)N * 64;
    float* q      = wsf;                      // N*64
    __half2* kv   = (__half2*)(q + N64);      // N*64 half2 (k,v packed)
    float* s      = (float*)(kv + N64);       // N*64 (skip proj)
    float* h1     = s + N64;                  // N*32
    float* h2     = h1 + (size_t)N * 32;      // N*64
    int* deg      = (int*)(h2 + N64);         // N
    int* rowptr   = deg + N;                  // N+1
    int* bsum     = rowptr + N + 1;           // SCAN_NB
    int* boff     = bsum + SCAN_NB;           // SCAN_NB
    int* rank     = boff + SCAN_NB;           // E
    int2* ecsr    = (int2*)(rank + E);        // E (packed {src, eattr})

    float* out = (float*)d_out;

    // ---- CSR build overlapped with linear4-L1 ----
    hipMemsetAsync(deg, 0, (size_t)N * 4, stream);
    count_linear4_kernel<64, 32><<<CNT_NB / 2 * 3, 256, 0, stream>>>(
        dst, deg, rank, E,
        x, Wq1, bq1, Wk1, bk1, Wv1, bv1, Ws1, bs1, q, kv, s, N);
    blocksum_kernel<<<SCAN_NB, 256, 0, stream>>>(deg, bsum, N);
    scanb_kernel<<<1, 256, 0, stream>>>(bsum, boff, rowptr + N, SCAN_NB);
    writeptr_kernel<<<SCAN_NB, 256, 0, stream>>>(deg, boff, rowptr, N);
    fill_pack_kernel<<<4096, 256, 0, stream>>>(src, dst, ea, rowptr, rank, ecsr, E);

    const int convGrid = (N + 3) / 4;

    // ---- layer 1 conv (C=32) ----
    conv_fused_kernel<32><<<convGrid, 256, 0, stream>>>(
        rowptr, ecsr, q, kv, s, We1, be1, h1, 0.17677669529663687f, N);

    // ---- layer 2 (C=64) ----
    linear4_mfma_kernel<32, 64><<<1024, 256, 0, stream>>>(
        h1, Wq2, bq2, Wk2, bk2, Wv2, bv2, Ws2, bs2, q, kv, s, N);
    conv_fused_kernel<64><<<convGrid, 256, 0, stream>>>(
        rowptr, ecsr, q, kv, s, We2, be2, h2, 0.125f, N);

    // ---- fused MLP head: fc1 + ELU + fc2 + log_softmax ----
    linear_head_mfma_kernel<64, 128, 10><<<1024, 256, 0, stream>>>(
        h2, Wf1, bf1, Wf2, bf2, out, N);
}

// Round 19
// 298.099 us; speedup vs baseline: 1.2470x; 1.0122x over previous
//
#include <hip/hip_runtime.h>
#include <hip/hip_fp16.h>
#include <math.h>

// TransformerConvNet: 2x TransformerConv(heads=1) + ELU + MLP head + log_softmax
// N=100000 nodes, E=1600000 edges, F_IN=64, C1=32, C2=64, H1=128, NC=10
//
// R19: u32 byte-offset addressing (base + zext(u32) -> global_load saddr form)
// in conv_fused hot loop and MFMA X-loads — kills 64-bit mul/carry address
// chains. Structure otherwise identical to R17.

#define SCAN_NB 256

typedef _Float16 half8 __attribute__((ext_vector_type(8)));
typedef float f32x4 __attribute__((ext_vector_type(4)));

// ---------- CSR build ----------
__global__ __launch_bounds__(256)
void blocksum_kernel(const int* __restrict__ deg, int* __restrict__ bsum, int n) {
    __shared__ int ls[256];
    const int chunk = (n + gridDim.x - 1) / gridDim.x;
    const int b0 = blockIdx.x * chunk;
    const int b1 = (b0 + chunk < n) ? b0 + chunk : n;
    int s = 0;
    for (int i = b0 + threadIdx.x; i < b1; i += 256) s += deg[i];
    ls[threadIdx.x] = s;
    __syncthreads();
    for (int off = 128; off > 0; off >>= 1) {
        if (threadIdx.x < off) ls[threadIdx.x] += ls[threadIdx.x + off];
        __syncthreads();
    }
    if (threadIdx.x == 0) bsum[blockIdx.x] = ls[0];
}

__global__ __launch_bounds__(256)
void scanb_kernel(const int* __restrict__ bsum, int* __restrict__ boff,
                  int* __restrict__ total, int nb) {
    __shared__ int ls[256];
    const int t = threadIdx.x;
    int v = (t < nb) ? bsum[t] : 0;
    ls[t] = v;
    __syncthreads();
    for (int off = 1; off < 256; off <<= 1) {
        int u = (t >= off) ? ls[t - off] : 0;
        __syncthreads();
        ls[t] += u;
        __syncthreads();
    }
    if (t < nb) boff[t] = ls[t] - v;
    if (t == 255) *total = ls[255];
}

__global__ __launch_bounds__(256)
void writeptr_kernel(const int* __restrict__ deg, const int* __restrict__ boff,
                     int* __restrict__ rowptr, int n) {
    __shared__ int ls[256];
    const int chunk = (n + gridDim.x - 1) / gridDim.x;
    const int b0 = blockIdx.x * chunk;
    const int b1 = (b0 + chunk < n) ? b0 + chunk : n;
    const int tchunk = (chunk + 255) / 256;
    const int t0 = b0 + threadIdx.x * tchunk;
    const int t1 = (t0 + tchunk < b1) ? t0 + tchunk : b1;
    int s = 0;
    for (int i = t0; i < t1; ++i) s += deg[i];
    ls[threadIdx.x] = s;
    __syncthreads();
    for (int off = 1; off < 256; off <<= 1) {
        int u = (threadIdx.x >= off) ? ls[threadIdx.x - off] : 0;
        __syncthreads();
        ls[threadIdx.x] += u;
        __syncthreads();
    }
    int run = boff[blockIdx.x] + ls[threadIdx.x] - s;
    for (int i = t0; i < t1; ++i) { rowptr[i] = run; run += deg[i]; }
}

__global__ __launch_bounds__(256)
void fill_pack_kernel(const int* __restrict__ src, const int* __restrict__ dst,
                      const float* __restrict__ eattr,
                      const int* __restrict__ rowptr, const int* __restrict__ rank,
                      int2* __restrict__ ecsr, int e) {
    char* eB = (char*)ecsr;
    for (int i = blockIdx.x * 256 + threadIdx.x; i < e; i += gridDim.x * 256) {
        unsigned p = (unsigned)(rowptr[dst[i]] + rank[i]) * 8u;
        *(int2*)(eB + p) = make_int2(src[i], __float_as_int(eattr[i]));
    }
}

// ---------- fused: count_rank (blocks role<2) + linear4-L1 MFMA (role==2) ----------
#define CNT_NB 2048
#define L4_NB  1024
template<int FIN, int C>
__global__ __launch_bounds__(256, 2)
void count_linear4_kernel(const int* __restrict__ dst, int* __restrict__ deg,
                          int* __restrict__ rank, int e,
                          const float* __restrict__ X,
                          const float* __restrict__ Wq, const float* __restrict__ bq,
                          const float* __restrict__ Wk, const float* __restrict__ bk,
                          const float* __restrict__ Wv, const float* __restrict__ bv,
                          const float* __restrict__ Ws, const float* __restrict__ bs,
                          float* __restrict__ q, __half2* __restrict__ kv,
                          float* __restrict__ s, int n)
{
    constexpr int FOURC = 4 * C;
    constexpr int P  = FIN + 16;
    constexpr int KT = FIN / 32;
    constexpr int NT = FOURC / 16;
    __shared__ _Float16 wsh[FOURC * P] __attribute__((aligned(16)));
    __shared__ float bsh[FOURC];

    const int b3 = blockIdx.x / 3, role = blockIdx.x % 3;
    if (role < 2) {
        const int cb = b3 * 2 + role;
        for (int i = cb * 256 + threadIdx.x; i < e; i += CNT_NB * 256)
            rank[i] = atomicAdd(deg + dst[i], 1);
        return;
    }

    const int lb = b3;
    for (int i = threadIdx.x; i < FOURC * FIN; i += 256) {
        int col = i / FIN, f = i - (i / FIN) * FIN;
        float w;
        if (col < C)          w = Wq[f * C + col];
        else if (col < 2 * C) w = Ws[f * C + col - C];
        else if (col < 3 * C) w = Wk[f * C + col - 2 * C];
        else                  w = Wv[f * C + col - 3 * C];
        wsh[col * P + f] = (_Float16)w;
    }
    for (int i = threadIdx.x; i < FOURC; i += 256) {
        bsh[i] = (i < C) ? bq[i] : (i < 2 * C) ? bs[i - C]
               : (i < 3 * C) ? bk[i - 2 * C] : bv[i - 3 * C];
    }
    __syncthreads();

    const int lane = threadIdx.x & 63;
    const int wid  = threadIdx.x >> 6;
    const int m = lane & 15, g = lane >> 4;

    half8 bfrag[KT][NT];
    #pragma unroll
    for (int kt = 0; kt < KT; ++kt)
        #pragma unroll
        for (int nt = 0; nt < NT; ++nt)
            bfrag[kt][nt] = *reinterpret_cast<const half8*>(
                &wsh[(nt * 16 + m) * P + kt * 32 + g * 8]);

    const char* XB = (const char*)X;
    const int tiles = n >> 4;
    for (int t = lb * 4 + wid; t < tiles; t += L4_NB * 4) {
        const int row0 = t * 16;
        const unsigned xoff = (unsigned)(row0 + m) * (unsigned)(FIN * 4) + (unsigned)(g * 32);
        half8 afrag[KT];
        #pragma unroll
        for (int kt = 0; kt < KT; ++kt) {
            float4 u = *(const float4*)(XB + xoff + kt * 128);
            float4 w = *(const float4*)(XB + xoff + kt * 128 + 16);
            afrag[kt] = half8{(_Float16)u.x, (_Float16)u.y, (_Float16)u.z, (_Float16)u.w,
                              (_Float16)w.x, (_Float16)w.y, (_Float16)w.z, (_Float16)w.w};
        }
        #pragma unroll
        for (int nt = 0; nt < 2 * C / 16; ++nt) {
            f32x4 acc = {0.f, 0.f, 0.f, 0.f};
            #pragma unroll
            for (int kt = 0; kt < KT; ++kt)
                acc = __builtin_amdgcn_mfma_f32_16x16x32_f16(afrag[kt], bfrag[kt][nt], acc, 0, 0, 0);
            const int col = nt * 16 + m;
            const float bias = bsh[col];
            float* outp = (nt < C / 16) ? q : s;
            const int cc = (nt < C / 16) ? col : col - C;
            #pragma unroll
            for (int r = 0; r < 4; ++r)
                outp[(size_t)(row0 + g * 4 + r) * C + cc] = acc[r] + bias;
        }
        #pragma unroll
        for (int t2 = 0; t2 < C / 16; ++t2) {
            const int ntK = 2 * C / 16 + t2, ntV = 3 * C / 16 + t2;
            f32x4 aK = {0.f, 0.f, 0.f, 0.f}, aV = {0.f, 0.f, 0.f, 0.f};
            #pragma unroll
            for (int kt = 0; kt < KT; ++kt) {
                aK = __builtin_amdgcn_mfma_f32_16x16x32_f16(afrag[kt], bfrag[kt][ntK], aK, 0, 0, 0);
                aV = __builtin_amdgcn_mfma_f32_16x16x32_f16(afrag[kt], bfrag[kt][ntV], aV, 0, 0, 0);
            }
            const int ck = t2 * 16 + m;
            const float bK = bsh[2 * C + ck], bV = bsh[3 * C + ck];
            #pragma unroll
            for (int r = 0; r < 4; ++r)
                kv[(size_t)(row0 + g * 4 + r) * C + ck] = __floats2half2_rn(aK[r] + bK, aV[r] + bV);
        }
    }
}

// ---------- linear4 via MFMA (layer 2): q | s (fp32) + kv (__half2) ----------
template<int FIN, int C>
__global__ __launch_bounds__(256, 2)
void linear4_mfma_kernel(const float* __restrict__ X,
                         const float* __restrict__ Wq, const float* __restrict__ bq,
                         const float* __restrict__ Wk, const float* __restrict__ bk,
                         const float* __restrict__ Wv, const float* __restrict__ bv,
                         const float* __restrict__ Ws, const float* __restrict__ bs,
                         float* __restrict__ q, __half2* __restrict__ kv,
                         float* __restrict__ s, int n)
{
    constexpr int FOURC = 4 * C;
    constexpr int P  = FIN + 16;
    constexpr int KT = FIN / 32;
    constexpr int NT = FOURC / 16;
    __shared__ _Float16 wsh[FOURC * P] __attribute__((aligned(16)));
    __shared__ float bsh[FOURC];

    for (int i = threadIdx.x; i < FOURC * FIN; i += 256) {
        int col = i / FIN, f = i - (i / FIN) * FIN;
        float w;
        if (col < C)          w = Wq[f * C + col];
        else if (col < 2 * C) w = Ws[f * C + col - C];
        else if (col < 3 * C) w = Wk[f * C + col - 2 * C];
        else                  w = Wv[f * C + col - 3 * C];
        wsh[col * P + f] = (_Float16)w;
    }
    for (int i = threadIdx.x; i < FOURC; i += 256) {
        bsh[i] = (i < C) ? bq[i] : (i < 2 * C) ? bs[i - C]
               : (i < 3 * C) ? bk[i - 2 * C] : bv[i - 3 * C];
    }
    __syncthreads();

    const int lane = threadIdx.x & 63;
    const int wid  = threadIdx.x >> 6;
    const int m = lane & 15, g = lane >> 4;

    half8 bfrag[KT][NT];
    #pragma unroll
    for (int kt = 0; kt < KT; ++kt)
        #pragma unroll
        for (int nt = 0; nt < NT; ++nt)
            bfrag[kt][nt] = *reinterpret_cast<const half8*>(
                &wsh[(nt * 16 + m) * P + kt * 32 + g * 8]);

    const char* XB = (const char*)X;
    const int tiles = n >> 4;
    for (int t = blockIdx.x * 4 + wid; t < tiles; t += gridDim.x * 4) {
        const int row0 = t * 16;
        const unsigned xoff = (unsigned)(row0 + m) * (unsigned)(FIN * 4) + (unsigned)(g * 8 * 4);
        half8 afrag[KT];
        #pragma unroll
        for (int kt = 0; kt < KT; ++kt) {
            float4 u = *(const float4*)(XB + xoff + kt * 128);
            float4 w = *(const float4*)(XB + xoff + kt * 128 + 16);
            afrag[kt] = half8{(_Float16)u.x, (_Float16)u.y, (_Float16)u.z, (_Float16)u.w,
                              (_Float16)w.x, (_Float16)w.y, (_Float16)w.z, (_Float16)w.w};
        }
        #pragma unroll
        for (int nt = 0; nt < 2 * C / 16; ++nt) {
            f32x4 acc = {0.f, 0.f, 0.f, 0.f};
            #pragma unroll
            for (int kt = 0; kt < KT; ++kt)
                acc = __builtin_amdgcn_mfma_f32_16x16x32_f16(afrag[kt], bfrag[kt][nt], acc, 0, 0, 0);
            const int col = nt * 16 + m;
            const float bias = bsh[col];
            float* outp = (nt < C / 16) ? q : s;
            const int cc = (nt < C / 16) ? col : col - C;
            #pragma unroll
            for (int r = 0; r < 4; ++r)
                outp[(size_t)(row0 + g * 4 + r) * C + cc] = acc[r] + bias;
        }
        #pragma unroll
        for (int t2 = 0; t2 < C / 16; ++t2) {
            const int ntK = 2 * C / 16 + t2, ntV = 3 * C / 16 + t2;
            f32x4 aK = {0.f, 0.f, 0.f, 0.f}, aV = {0.f, 0.f, 0.f, 0.f};
            #pragma unroll
            for (int kt = 0; kt < KT; ++kt) {
                aK = __builtin_amdgcn_mfma_f32_16x16x32_f16(afrag[kt], bfrag[kt][ntK], aK, 0, 0, 0);
                aV = __builtin_amdgcn_mfma_f32_16x16x32_f16(afrag[kt], bfrag[kt][ntV], aV, 0, 0, 0);
            }
            const int ck = t2 * 16 + m;
            const float bK = bsh[2 * C + ck], bV = bsh[3 * C + ck];
            #pragma unroll
            for (int r = 0; r < 4; ++r)
                kv[(size_t)(row0 + g * 4 + r) * C + ck] = __floats2half2_rn(aK[r] + bK, aV[r] + bV);
        }
    }
}

// ---------- fused conv: 4 ch/lane, factored e-term, masked unroll, u32 addressing ----------
template<int C>
__global__ __launch_bounds__(256)
void conv_fused_kernel(const int* __restrict__ rowptr, const int2* __restrict__ ecsr,
                       const float* __restrict__ q, const __half2* __restrict__ kv,
                       const float* __restrict__ sres,
                       const float* __restrict__ We, const float* __restrict__ be,
                       float* __restrict__ h, float scale, int n)
{
    constexpr int LPE    = C / 4;
    constexpr int EPI    = 64 / LPE;
    constexpr int LOG    = (C == 64) ? 4 : 3;
    constexpr int UNROLL = (C == 64) ? 4 : 2;
    const int wave = threadIdx.x >> 6;
    const int lane = threadIdx.x & 63;
    const int l    = lane & (LPE - 1);
    const int slot = lane >> LOG;
    const int c0   = 4 * l;
    const int node = blockIdx.x * 4 + wave;
    if (node >= n) return;

    const char* kvB = (const char*)kv;
    const char* eB  = (const char*)ecsr;
    const unsigned cb0 = (unsigned)(c0 * 4);           // byte offset of this lane's 4 channels

    const float4 wec = *reinterpret_cast<const float4*>(We + c0);
    const float4 bec = *reinterpret_cast<const float4*>(be + c0);
    const float4 qp  = *(const float4*)((const char*)q + (unsigned)node * (unsigned)(C * 4) + cb0);
    const int r0 = rowptr[node], r1 = rowptr[node + 1];

    float pd1 = fmaf(qp.x, wec.x, fmaf(qp.y, wec.y, fmaf(qp.z, wec.z, qp.w * wec.w)));
    float pd0 = fmaf(qp.x, bec.x, fmaf(qp.y, bec.y, fmaf(qp.z, bec.z, qp.w * bec.w)));
    #pragma unroll
    for (int off = LPE >> 1; off > 0; off >>= 1) {
        pd1 += __shfl_xor(pd1, off);
        pd0 += __shfl_xor(pd0, off);
    }
    const float sd1 = pd1 * scale, sd0 = pd0 * scale;

    float ssum = 0.f, swea = 0.f;
    float a0 = 0.f, a1 = 0.f, a2 = 0.f, a3 = 0.f;
    const int j0 = r0 + slot;
    const int iters = (r1 - j0 + EPI - 1) / EPI;
    for (int it = 0; it < iters; it += UNROLL) {
        int2 epk[UNROLL]; float4 kvr[UNROLL]; bool ok[UNROLL];
        #pragma unroll
        for (int u = 0; u < UNROLL; ++u) {
            int j = j0 + (it + u) * EPI;
            ok[u] = j < r1;
            unsigned joff = (unsigned)(ok[u] ? j : r0) * 8u;
            epk[u] = *(const int2*)(eB + joff);
        }
        #pragma unroll
        for (int u = 0; u < UNROLL; ++u) {
            unsigned koff = (unsigned)epk[u].x * (unsigned)(C * 4) + cb0;
            kvr[u] = *(const float4*)(kvB + koff);
        }
        #pragma unroll
        for (int u = 0; u < UNROLL; ++u) {
            float ea = __int_as_float(epk[u].y);
            float2 f0 = __half22float2(*reinterpret_cast<__half2*>(&kvr[u].x));
            float2 f1 = __half22float2(*reinterpret_cast<__half2*>(&kvr[u].y));
            float2 f2 = __half22float2(*reinterpret_cast<__half2*>(&kvr[u].z));
            float2 f3 = __half22float2(*reinterpret_cast<__half2*>(&kvr[u].w));
            float p = fmaf(qp.x, f0.x, fmaf(qp.y, f1.x, fmaf(qp.z, f2.x, qp.w * f3.x)));
            #pragma unroll
            for (int off = LPE >> 1; off > 0; off >>= 1) p += __shfl_xor(p, off);
            float w = __expf(fmaf(scale, p, fmaf(sd1, ea, sd0)));
            w = ok[u] ? w : 0.f;
            ssum += w;
            swea = fmaf(w, ea, swea);
            a0 = fmaf(w, f0.y, a0);
            a1 = fmaf(w, f1.y, a1);
            a2 = fmaf(w, f2.y, a2);
            a3 = fmaf(w, f3.y, a3);
        }
    }

    #pragma unroll
    for (int off = LPE; off < 64; off <<= 1) {
        ssum += __shfl_xor(ssum, off);
        swea += __shfl_xor(swea, off);
        a0   += __shfl_xor(a0, off);
        a1   += __shfl_xor(a1, off);
        a2   += __shfl_xor(a2, off);
        a3   += __shfl_xor(a3, off);
    }

    if (slot == 0) {
        float inv = 1.f / (ssum + 1e-16f);
        float t0 = fmaf(wec.x, swea, fmaf(bec.x, ssum, a0));
        float t1 = fmaf(wec.y, swea, fmaf(bec.y, ssum, a1));
        float t2 = fmaf(wec.z, swea, fmaf(bec.z, ssum, a2));
        float t3 = fmaf(wec.w, swea, fmaf(bec.w, ssum, a3));
        float4 sr = *(const float4*)((const char*)sres + (unsigned)node * (unsigned)(C * 4) + cb0);
        float h0 = fmaf(t0, inv, sr.x);
        float h1 = fmaf(t1, inv, sr.y);
        float h2v = fmaf(t2, inv, sr.z);
        float h3 = fmaf(t3, inv, sr.w);
        h0 = (h0 > 0.f) ? h0 : expm1f(h0);
        h1 = (h1 > 0.f) ? h1 : expm1f(h1);
        h2v = (h2v > 0.f) ? h2v : expm1f(h2v);
        h3 = (h3 > 0.f) ? h3 : expm1f(h3);
        *(float4*)((char*)h + (unsigned)node * (unsigned)(C * 4) + cb0) = make_float4(h0, h1, h2v, h3);
    }
}

// ---------- fused head: fc1 MFMA + ELU -> LDS transpose -> fc2 MFMA + log_softmax ----------
template<int FIN, int COUT, int NCLS>
__global__ __launch_bounds__(256, 2)
void linear_head_mfma_kernel(const float* __restrict__ X,
                             const float* __restrict__ W1, const float* __restrict__ b1,
                             const float* __restrict__ W2, const float* __restrict__ b2,
                             float* __restrict__ out, int n)
{
    constexpr int P   = FIN + 16;    // 80
    constexpr int KT  = FIN / 32;    // 2
    constexpr int NT  = COUT / 16;   // 8
    constexpr int KT2 = COUT / 32;   // 4
    constexpr int HP  = COUT + 8;    // 136
    __shared__ _Float16 wsh[COUT * P] __attribute__((aligned(16)));
    __shared__ float bsh[COUT];
    __shared__ _Float16 hsh[4][16 * HP] __attribute__((aligned(16)));
    __shared__ float b2sh[NCLS];

    for (int i = threadIdx.x; i < COUT * FIN; i += 256) {
        int col = i / FIN, f = i - (i / FIN) * FIN;
        wsh[col * P + f] = (_Float16)W1[f * COUT + col];
    }
    for (int i = threadIdx.x; i < COUT; i += 256) bsh[i] = b1[i];
    for (int i = threadIdx.x; i < NCLS; i += 256) b2sh[i] = b2[i];
    __syncthreads();

    const int lane = threadIdx.x & 63;
    const int wid  = threadIdx.x >> 6;
    const int m = lane & 15, g = lane >> 4;

    half8 bfrag[KT][NT];
    #pragma unroll
    for (int kt = 0; kt < KT; ++kt)
        #pragma unroll
        for (int nt = 0; nt < NT; ++nt)
            bfrag[kt][nt] = *reinterpret_cast<const half8*>(
                &wsh[(nt * 16 + m) * P + kt * 32 + g * 8]);

    half8 bfrag2[KT2];
    #pragma unroll
    for (int kt = 0; kt < KT2; ++kt) {
        half8 tt;
        #pragma unroll
        for (int j = 0; j < 8; ++j) {
            float w = (m < NCLS) ? W2[(kt * 32 + g * 8 + j) * NCLS + m] : 0.f;
            tt[j] = (_Float16)w;
        }
        bfrag2[kt] = tt;
    }

    _Float16* hrow = &hsh[wid][0];
    const char* XB = (const char*)X;
    const int tiles = n >> 4;
    for (int t = blockIdx.x * 4 + wid; t < tiles; t += gridDim.x * 4) {
        const int row0 = t * 16;
        const unsigned xoff = (unsigned)(row0 + m) * (unsigned)(FIN * 4) + (unsigned)(g * 32);
        half8 afrag[KT];
        #pragma unroll
        for (int kt = 0; kt < KT; ++kt) {
            float4 u = *(const float4*)(XB + xoff + kt * 128);
            float4 w = *(const float4*)(XB + xoff + kt * 128 + 16);
            afrag[kt] = half8{(_Float16)u.x, (_Float16)u.y, (_Float16)u.z, (_Float16)u.w,
                              (_Float16)w.x, (_Float16)w.y, (_Float16)w.z, (_Float16)w.w};
        }
        #pragma unroll
        for (int nt = 0; nt < NT; ++nt) {
            f32x4 acc = {0.f, 0.f, 0.f, 0.f};
            #pragma unroll
            for (int kt = 0; kt < KT; ++kt)
                acc = __builtin_amdgcn_mfma_f32_16x16x32_f16(afrag[kt], bfrag[kt][nt], acc, 0, 0, 0);
            const float bias = bsh[nt * 16 + m];
            #pragma unroll
            for (int r = 0; r < 4; ++r) {
                float v = acc[r] + bias;
                v = (v > 0.f) ? v : expm1f(v);
                hrow[(g * 4 + r) * HP + nt * 16 + m] = (_Float16)v;
            }
        }
        f32x4 acc2 = {0.f, 0.f, 0.f, 0.f};
        #pragma unroll
        for (int kt = 0; kt < KT2; ++kt) {
            half8 a2 = *reinterpret_cast<const half8*>(&hrow[m * HP + kt * 32 + g * 8]);
            acc2 = __builtin_amdgcn_mfma_f32_16x16x32_f16(a2, bfrag2[kt], acc2, 0, 0, 0);
        }
        #pragma unroll
        for (int r = 0; r < 4; ++r) {
            float logit = acc2[r] + ((m < NCLS) ? b2sh[m] : -1e30f);
            float mx = logit;
            #pragma unroll
            for (int off = 1; off < 16; off <<= 1) mx = fmaxf(mx, __shfl_xor(mx, off));
            float ex = (m < NCLS) ? __expf(logit - mx) : 0.f;
            float sum = ex;
            #pragma unroll
            for (int off = 1; off < 16; off <<= 1) sum += __shfl_xor(sum, off);
            float lse = mx + logf(sum);
            if (m < NCLS)
                out[(size_t)(row0 + g * 4 + r) * NCLS + m] = logit - lse;
        }
    }
}

extern "C" void kernel_launch(void* const* d_in, const int* in_sizes, int n_in,
                              void* d_out, int out_size, void* d_ws, size_t ws_size,
                              hipStream_t stream) {
    const float* x   = (const float*)d_in[0];
    const int*   ei  = (const int*)d_in[1];
    const float* ea  = (const float*)d_in[2];
    const float *Wq1 = (const float*)d_in[3],  *bq1 = (const float*)d_in[4];
    const float *Wk1 = (const float*)d_in[5],  *bk1 = (const float*)d_in[6];
    const float *Wv1 = (const float*)d_in[7],  *bv1 = (const float*)d_in[8];
    const float *We1 = (const float*)d_in[9],  *be1 = (const float*)d_in[10];
    const float *Ws1 = (const float*)d_in[11], *bs1 = (const float*)d_in[12];
    const float *Wq2 = (const float*)d_in[13], *bq2 = (const float*)d_in[14];
    const float *Wk2 = (const float*)d_in[15], *bk2 = (const float*)d_in[16];
    const float *Wv2 = (const float*)d_in[17], *bv2 = (const float*)d_in[18];
    const float *We2 = (const float*)d_in[19], *be2 = (const float*)d_in[20];
    const float *Ws2 = (const float*)d_in[21], *bs2 = (const float*)d_in[22];
    const float *Wf1 = (const float*)d_in[23], *bf1 = (const float*)d_in[24];
    const float *Wf2 = (const float*)d_in[25], *bf2 = (const float*)d_in[26];

    const int N = in_sizes[0] / 64;   // 100000
    const int E = in_sizes[2];        // 1600000
    const int* src = ei;              // edge_index[0]
    const int* dst = ei + E;          // edge_index[1]

    float* wsf = (float*)d_ws;
    const size_t N64 = (size_t)N * 64;
    float* q      = wsf;                      // N*64
    __half2* kv   = (__half2*)(q + N64);      // N*64 half2 (k,v packed)
    float* s      = (float*)(kv + N64);       // N*64 (skip proj)
    float* h1     = s + N64;                  // N*32
    float* h2     = h1 + (size_t)N * 32;      // N*64
    int* deg      = (int*)(h2 + N64);         // N
    int* rowptr   = deg + N;                  // N+1
    int* bsum     = rowptr + N + 1;           // SCAN_NB
    int* boff     = bsum + SCAN_NB;           // SCAN_NB
    int* rank     = boff + SCAN_NB;           // E
    int2* ecsr    = (int2*)(rank + E);        // E (packed {src, eattr})

    float* out = (float*)d_out;

    // ---- CSR build overlapped with linear4-L1 ----
    hipMemsetAsync(deg, 0, (size_t)N * 4, stream);
    count_linear4_kernel<64, 32><<<CNT_NB / 2 * 3, 256, 0, stream>>>(
        dst, deg, rank, E,
        x, Wq1, bq1, Wk1, bk1, Wv1, bv1, Ws1, bs1, q, kv, s, N);
    blocksum_kernel<<<SCAN_NB, 256, 0, stream>>>(deg, bsum, N);
    scanb_kernel<<<1, 256, 0, stream>>>(bsum, boff, rowptr + N, SCAN_NB);
    writeptr_kernel<<<SCAN_NB, 256, 0, stream>>>(deg, boff, rowptr, N);
    fill_pack_kernel<<<4096, 256, 0, stream>>>(src, dst, ea, rowptr, rank, ecsr, E);

    const int convGrid = (N + 3) / 4;

    // ---- layer 1 conv (C=32) ----
    conv_fused_kernel<32><<<convGrid, 256, 0, stream>>>(
        rowptr, ecsr, q, kv, s, We1, be1, h1, 0.17677669529663687f, N);

    // ---- layer 2 (C=64) ----
    linear4_mfma_kernel<32, 64><<<1024, 256, 0, stream>>>(
        h1, Wq2, bq2, Wk2, bk2, Wv2, bv2, Ws2, bs2, q, kv, s, N);
    conv_fused_kernel<64><<<convGrid, 256, 0, stream>>>(
        rowptr, ecsr, q, kv, s, We2, be2, h2, 0.125f, N);

    // ---- fused MLP head: fc1 + ELU + fc2 + log_softmax ----
    linear_head_mfma_kernel<64, 128, 10><<<1024, 256, 0, stream>>>(
        h2, Wf1, bf1, Wf2, bf2, out, N);
}